// Round 1
// baseline (2281.655 us; speedup 1.0000x reference)
//
#include <hip/hip_runtime.h>
#include <math.h>

// GCN 2-layer forward on MI355X.
// Layout constants: C_IN = C_OUT = 128 channels everywhere.
#define CH   128
#define CH4  32          // CH / 4 (float4 granularity)
#define TPB  256

// ---------------------------------------------------------------------------
// degree / normalization
// ---------------------------------------------------------------------------
__global__ void k_init_deg(float* __restrict__ deg, int n) {
    int i = blockIdx.x * blockDim.x + threadIdx.x;
    if (i < n) deg[i] = 1.0f;   // self-loop weight
}

__global__ void k_scatter_deg(const int* __restrict__ dst, const float* __restrict__ ew,
                              float* __restrict__ deg, int E, int n) {
    int e = blockIdx.x * blockDim.x + threadIdx.x;
    if (e < E) {
        int d = dst[e];
        if ((unsigned)d < (unsigned)n)   // guard: no OOB even if indices are garbage
            unsafeAtomicAdd(&deg[d], ew[e]);
    }
}

__global__ void k_dinv(float* __restrict__ deg, int n) {
    int i = blockIdx.x * blockDim.x + threadIdx.x;
    if (i < n) {
        float d = deg[i];
        deg[i] = (d > 0.0f) ? rsqrtf(d) : 0.0f;  // in-place: deg becomes dinv
    }
}

// ---------------------------------------------------------------------------
// H = (relu?)(X) @ W   — fp32 vector GEMM, W (64 KB) staged in LDS.
// Thread layout: 8 rows/tile, 32 threads/row, each thread owns 4 output cols.
// Grid-stride over row tiles so W is loaded into LDS only gridDim times.
// ---------------------------------------------------------------------------
template<int RELU_IN>
__global__ __launch_bounds__(TPB, 2)
void k_gemm(const float* __restrict__ X, const float* __restrict__ W,
            float* __restrict__ H, int n) {
    __shared__ float sW[CH * CH];          // 64 KB -> 2 blocks/CU
    float4* sW4 = (float4*)sW;
    const float4* W4 = (const float4*)W;
    for (int i = threadIdx.x; i < CH * CH4; i += TPB) sW4[i] = W4[i];
    __syncthreads();

    const int tx = threadIdx.x & 31;       // col group (4 cols)
    const int ty = threadIdx.x >> 5;       // row within 8-row tile
    const float4* X4 = (const float4*)X;

    for (int row0 = blockIdx.x * 8; row0 < n; row0 += gridDim.x * 8) {
        int r = row0 + ty;
        if (r >= n) continue;              // no barriers in loop body, safe
        const float4* xrow = X4 + (size_t)r * CH4;
        float4 acc = make_float4(0.f, 0.f, 0.f, 0.f);
        #pragma unroll 4
        for (int k4 = 0; k4 < CH4; ++k4) {
            float4 xv = xrow[k4];          // same addr across 32 lanes: broadcast
            if (RELU_IN) {
                xv.x = fmaxf(xv.x, 0.f); xv.y = fmaxf(xv.y, 0.f);
                xv.z = fmaxf(xv.z, 0.f); xv.w = fmaxf(xv.w, 0.f);
            }
            float4 w0 = sW4[(k4 * 4 + 0) * CH4 + tx];
            float4 w1 = sW4[(k4 * 4 + 1) * CH4 + tx];
            float4 w2 = sW4[(k4 * 4 + 2) * CH4 + tx];
            float4 w3 = sW4[(k4 * 4 + 3) * CH4 + tx];
            acc.x += xv.x * w0.x + xv.y * w1.x + xv.z * w2.x + xv.w * w3.x;
            acc.y += xv.x * w0.y + xv.y * w1.y + xv.z * w2.y + xv.w * w3.y;
            acc.z += xv.x * w0.z + xv.y * w1.z + xv.z * w2.z + xv.w * w3.z;
            acc.w += xv.x * w0.w + xv.y * w1.w + xv.z * w2.w + xv.w * w3.w;
        }
        ((float4*)H)[(size_t)r * CH4 + tx] = acc;
    }
}

// ---------------------------------------------------------------------------
// Out[n][:] = H[n][:] * dinv[n]^2 + bias   (self-loop message + bias)
// Fully initializes Out (required: d_out/d_ws are poisoned before each call).
// ---------------------------------------------------------------------------
__global__ void k_agg_init(const float* __restrict__ H, const float* __restrict__ dinv,
                           const float* __restrict__ bias, float* __restrict__ Out, int n) {
    int i = blockIdx.x * blockDim.x + threadIdx.x;  // over n * CH4 float4s
    if (i >= n * CH4) return;
    int r = i >> 5;
    int c = i & 31;
    float di = dinv[r];
    float sc = di * di;
    float4 h = ((const float4*)H)[i];
    float4 b = ((const float4*)bias)[c];
    ((float4*)Out)[i] = make_float4(h.x * sc + b.x, h.y * sc + b.y,
                                    h.z * sc + b.z, h.w * sc + b.w);
}

// ---------------------------------------------------------------------------
// Edge scatter: Out[dst] += H[src] * (dinv[src]*ew*dinv[dst])
// 32 threads per edge, each handles 4 channels (float4 gather + 4 fp32 atomics).
// ---------------------------------------------------------------------------
__global__ __launch_bounds__(TPB)
void k_scatter(const int* __restrict__ src, const int* __restrict__ dst,
               const float* __restrict__ ew, const float* __restrict__ dinv,
               const float* __restrict__ H, float* __restrict__ Out, int E, int n) {
    int t = blockIdx.x * blockDim.x + threadIdx.x;
    int e = t >> 5;
    if (e >= E) return;
    int tx = t & 31;
    int s = src[e], d = dst[e];
    if ((unsigned)s >= (unsigned)n || (unsigned)d >= (unsigned)n) return;
    float norm = dinv[s] * ew[e] * dinv[d];
    float4 h = ((const float4*)H)[(size_t)s * CH4 + tx];
    float* op = Out + (size_t)d * CH + tx * 4;
    unsafeAtomicAdd(op + 0, h.x * norm);
    unsafeAtomicAdd(op + 1, h.y * norm);
    unsafeAtomicAdd(op + 2, h.z * norm);
    unsafeAtomicAdd(op + 3, h.w * norm);
}

__global__ void k_relu(float* __restrict__ X, int n4) {
    int i = blockIdx.x * blockDim.x + threadIdx.x;
    if (i < n4) {
        float4 v = ((float4*)X)[i];
        v.x = fmaxf(v.x, 0.f); v.y = fmaxf(v.y, 0.f);
        v.z = fmaxf(v.z, 0.f); v.w = fmaxf(v.w, 0.f);
        ((float4*)X)[i] = v;
    }
}

// ---------------------------------------------------------------------------
extern "C" void kernel_launch(void* const* d_in, const int* in_sizes, int n_in,
                              void* d_out, int out_size, void* d_ws, size_t ws_size,
                              hipStream_t stream) {
    const float* x  = (const float*)d_in[0];   // [N,128]
    const int*   ei = (const int*)d_in[1];     // [2,E]
    const float* ew = (const float*)d_in[2];   // [E]
    const float* W1 = (const float*)d_in[3];   // [128,128]
    const float* b1 = (const float*)d_in[4];   // [128]
    const float* W2 = (const float*)d_in[5];   // [128,128]
    const float* b2 = (const float*)d_in[6];   // [128]
    float* out = (float*)d_out;                // [N,128]

    const int N = in_sizes[0] / CH;
    const int E = in_sizes[2];
    const int* src = ei;
    const int* dst = ei + E;

    // workspace: dinv | h | out1   (all float4-aligned)
    float* ws   = (float*)d_ws;
    float* dinv = ws;                                   // N floats (deg -> dinv in place)
    float* h    = ws + (((size_t)N + 255) & ~(size_t)255);
    float* out1 = h + (size_t)N * CH;

    const int nbN  = (N + TPB - 1) / TPB;
    const int nbE  = (E + TPB - 1) / TPB;
    const int nbNC = (N * CH4 + TPB - 1) / TPB;
    const int nbEC = (int)(((size_t)E * 32 + TPB - 1) / TPB);
    const int gemm_grid = 2048;

    // normalization (shared by both layers)
    k_init_deg   <<<nbN, TPB, 0, stream>>>(dinv, N);
    k_scatter_deg<<<nbE, TPB, 0, stream>>>(dst, ew, dinv, E, N);
    k_dinv       <<<nbN, TPB, 0, stream>>>(dinv, N);

    // layer 1
    k_gemm<0>  <<<gemm_grid, TPB, 0, stream>>>(x, W1, h, N);
    k_agg_init <<<nbNC, TPB, 0, stream>>>(h, dinv, b1, out1, N);
    k_scatter  <<<nbEC, TPB, 0, stream>>>(src, dst, ew, dinv, h, out1, E, N);
    // relu(out1) fused into gemm2's load

    // layer 2
    k_gemm<1>  <<<gemm_grid, TPB, 0, stream>>>(out1, W2, h, N);
    k_agg_init <<<nbNC, TPB, 0, stream>>>(h, dinv, b2, out, N);
    k_scatter  <<<nbEC, TPB, 0, stream>>>(src, dst, ew, dinv, h, out, E, N);
    k_relu     <<<nbNC, TPB, 0, stream>>>(out, N * CH4);
}

// Round 2
// 404.944 us; speedup vs baseline: 5.6345x; 5.6345x over previous
//
#include <hip/hip_runtime.h>
#include <math.h>

// GCN 2-layer forward on MI355X — round 2: CSR-gather aggregation (no atomics
// in the hot path). CSR built per-call (same work every call, graph-safe).
#define CH   128
#define CH4  32          // CH / 4 (float4 granularity)
#define TPB  256
#define SCANB 1024

// ---------------------------------------------------------------------------
// init: deg = 1 (self-loop), counts = 0
// ---------------------------------------------------------------------------
__global__ void k_init(float* __restrict__ deg, int* __restrict__ counts, int n) {
    int i = blockIdx.x * blockDim.x + threadIdx.x;
    if (i < n) { deg[i] = 1.0f; counts[i] = 0; }
}

// per-edge: deg[dst] += ew; counts[dst] += 1
__global__ void k_edge_pass1(const int* __restrict__ dst, const float* __restrict__ ew,
                             float* __restrict__ deg, int* __restrict__ counts,
                             int E, int n) {
    int e = blockIdx.x * blockDim.x + threadIdx.x;
    if (e < E) {
        int d = dst[e];
        if ((unsigned)d < (unsigned)n) {
            unsafeAtomicAdd(&deg[d], ew[e]);
            atomicAdd(&counts[d], 1);
        }
    }
}

__global__ void k_dinv(float* __restrict__ deg, int n) {
    int i = blockIdx.x * blockDim.x + threadIdx.x;
    if (i < n) {
        float d = deg[i];
        deg[i] = (d > 0.0f) ? rsqrtf(d) : 0.0f;  // in-place: deg -> dinv
    }
}

// ---------------------------------------------------------------------------
// 3-pass exclusive prefix sum over counts[n] -> row_start[n]; partials scratch.
// ---------------------------------------------------------------------------
__global__ __launch_bounds__(SCANB)
void k_scan1(const int* __restrict__ counts, int* __restrict__ row_start,
             int* __restrict__ partials, int n) {
    __shared__ int s[SCANB];
    int gid = blockIdx.x * SCANB + threadIdx.x;
    int v = (gid < n) ? counts[gid] : 0;
    s[threadIdx.x] = v;
    __syncthreads();
    for (int off = 1; off < SCANB; off <<= 1) {
        int t = (threadIdx.x >= off) ? s[threadIdx.x - off] : 0;
        __syncthreads();
        s[threadIdx.x] += t;
        __syncthreads();
    }
    if (gid < n) row_start[gid] = s[threadIdx.x] - v;   // exclusive within block
    if (threadIdx.x == SCANB - 1) partials[blockIdx.x] = s[SCANB - 1];
}

__global__ __launch_bounds__(64)
void k_scan2(int* __restrict__ partials, int nb) {     // nb <= 64
    __shared__ int s[64];
    int v = (threadIdx.x < nb) ? partials[threadIdx.x] : 0;
    s[threadIdx.x] = v;
    __syncthreads();
    for (int off = 1; off < 64; off <<= 1) {
        int t = (threadIdx.x >= off) ? s[threadIdx.x - off] : 0;
        __syncthreads();
        s[threadIdx.x] += t;
        __syncthreads();
    }
    if (threadIdx.x < nb) partials[threadIdx.x] = s[threadIdx.x] - v;  // exclusive
}

__global__ __launch_bounds__(SCANB)
void k_scan3(int* __restrict__ row_start, const int* __restrict__ partials,
             int* __restrict__ cursor, int n) {
    int gid = blockIdx.x * SCANB + threadIdx.x;
    if (gid < n) {
        int v = row_start[gid] + partials[blockIdx.x];
        row_start[gid] = v;
        cursor[gid] = v;
    }
}

// per-edge: pos = cursor[dst]++; srcs[pos] = src; norms[pos] = full edge norm
__global__ void k_fill(const int* __restrict__ src, const int* __restrict__ dst,
                       const float* __restrict__ ew, const float* __restrict__ dinv,
                       int* __restrict__ cursor, int* __restrict__ srcs,
                       float* __restrict__ norms, int E, int n) {
    int e = blockIdx.x * blockDim.x + threadIdx.x;
    if (e >= E) return;
    int s = src[e], d = dst[e];
    if ((unsigned)s >= (unsigned)n || (unsigned)d >= (unsigned)n) return;
    int pos = atomicAdd(&cursor[d], 1);
    srcs[pos] = s;
    norms[pos] = dinv[s] * ew[e] * dinv[d];
}

// ---------------------------------------------------------------------------
// H = (relu?)(X) @ W — fp32 vector GEMM, W (64 KB) in LDS.
// 8 rows/tile, 32 threads/row, 4 output cols/thread, grid-stride over tiles.
// ---------------------------------------------------------------------------
template<int RELU_IN>
__global__ __launch_bounds__(TPB, 2)
void k_gemm(const float* __restrict__ X, const float* __restrict__ W,
            float* __restrict__ H, int n) {
    __shared__ float sW[CH * CH];
    float4* sW4 = (float4*)sW;
    const float4* W4 = (const float4*)W;
    for (int i = threadIdx.x; i < CH * CH4; i += TPB) sW4[i] = W4[i];
    __syncthreads();

    const int tx = threadIdx.x & 31;
    const int ty = threadIdx.x >> 5;
    const float4* X4 = (const float4*)X;

    for (int row0 = blockIdx.x * 8; row0 < n; row0 += gridDim.x * 8) {
        int r = row0 + ty;
        if (r >= n) continue;
        const float4* xrow = X4 + (size_t)r * CH4;
        float4 acc = make_float4(0.f, 0.f, 0.f, 0.f);
        #pragma unroll 4
        for (int k4 = 0; k4 < CH4; ++k4) {
            float4 xv = xrow[k4];
            if (RELU_IN) {
                xv.x = fmaxf(xv.x, 0.f); xv.y = fmaxf(xv.y, 0.f);
                xv.z = fmaxf(xv.z, 0.f); xv.w = fmaxf(xv.w, 0.f);
            }
            float4 w0 = sW4[(k4 * 4 + 0) * CH4 + tx];
            float4 w1 = sW4[(k4 * 4 + 1) * CH4 + tx];
            float4 w2 = sW4[(k4 * 4 + 2) * CH4 + tx];
            float4 w3 = sW4[(k4 * 4 + 3) * CH4 + tx];
            acc.x += xv.x * w0.x + xv.y * w1.x + xv.z * w2.x + xv.w * w3.x;
            acc.y += xv.x * w0.y + xv.y * w1.y + xv.z * w2.y + xv.w * w3.y;
            acc.z += xv.x * w0.z + xv.y * w1.z + xv.z * w2.z + xv.w * w3.z;
            acc.w += xv.x * w0.w + xv.y * w1.w + xv.z * w2.w + xv.w * w3.w;
        }
        ((float4*)H)[(size_t)r * CH4 + tx] = acc;
    }
}

// ---------------------------------------------------------------------------
// CSR aggregate: out[i] = (relu?)( h[i]*dinv[i]^2 + bias + sum_j h[srcs[j]]*norms[j] )
// 32 lanes per node (4 ch each), 8 nodes per 256-thread block.
// ---------------------------------------------------------------------------
template<int RELU_OUT>
__global__ __launch_bounds__(TPB)
void k_aggregate(const float* __restrict__ h, const int* __restrict__ row_start,
                 const int* __restrict__ counts, const int* __restrict__ srcs,
                 const float* __restrict__ norms, const float* __restrict__ dinv,
                 const float* __restrict__ bias, float* __restrict__ out, int n) {
    int t = blockIdx.x * blockDim.x + threadIdx.x;
    int node = t >> 5;
    if (node >= n) return;
    int tx = t & 31;

    float di = dinv[node];
    float sc = di * di;
    float4 b  = ((const float4*)bias)[tx];
    float4 hv = ((const float4*)h)[(size_t)node * CH4 + tx];
    float4 acc = make_float4(hv.x * sc + b.x, hv.y * sc + b.y,
                             hv.z * sc + b.z, hv.w * sc + b.w);

    int start = row_start[node];
    int end   = start + counts[node];
    for (int j = start; j < end; ++j) {
        int s     = srcs[j];    // uniform across the 32 lanes -> broadcast
        float nrm = norms[j];
        float4 g = ((const float4*)h)[(size_t)s * CH4 + tx];
        acc.x += g.x * nrm; acc.y += g.y * nrm;
        acc.z += g.z * nrm; acc.w += g.w * nrm;
    }
    if (RELU_OUT) {
        acc.x = fmaxf(acc.x, 0.f); acc.y = fmaxf(acc.y, 0.f);
        acc.z = fmaxf(acc.z, 0.f); acc.w = fmaxf(acc.w, 0.f);
    }
    ((float4*)out)[(size_t)node * CH4 + tx] = acc;
}

// ---------------------------------------------------------------------------
extern "C" void kernel_launch(void* const* d_in, const int* in_sizes, int n_in,
                              void* d_out, int out_size, void* d_ws, size_t ws_size,
                              hipStream_t stream) {
    const float* x  = (const float*)d_in[0];   // [N,128]
    const int*   ei = (const int*)d_in[1];     // [2,E] (harness delivers int32)
    const float* ew = (const float*)d_in[2];   // [E]
    const float* W1 = (const float*)d_in[3];
    const float* b1 = (const float*)d_in[4];
    const float* W2 = (const float*)d_in[5];
    const float* b2 = (const float*)d_in[6];
    float* out = (float*)d_out;                // [N,128]

    const int N = in_sizes[0] / CH;
    const int E = in_sizes[2];
    const int* src = ei;
    const int* dst = ei + E;

    // workspace layout (all 16B-aligned; N,E divisible by 4)
    size_t Np = ((size_t)N + 255) & ~(size_t)255;
    float* ws        = (float*)d_ws;
    float* dinv      = ws;                       // N floats
    float* h         = dinv + Np;                // N*CH floats
    int*   counts    = (int*)(h + (size_t)N * CH);  // N ints
    int*   row_start = counts + Np;              // N ints
    int*   cursor    = row_start + Np;           // N ints
    int*   partials  = cursor + Np;              // 64 ints
    int*   srcs      = partials + 64;            // E ints
    float* norms     = (float*)(srcs + E);       // E floats

    const int nbN   = (N + TPB - 1) / TPB;
    const int nbE   = (E + TPB - 1) / TPB;
    const int nbAgg = (int)(((size_t)N * 32 + TPB - 1) / TPB);
    const int nbScan = (N + SCANB - 1) / SCANB;  // 49 <= 64
    const int gemm_grid = 2048;

    // ---- CSR build + normalization (shared by both layers) ----
    k_init      <<<nbN, TPB, 0, stream>>>(dinv, counts, N);
    k_edge_pass1<<<nbE, TPB, 0, stream>>>(dst, ew, dinv, counts, E, N);
    k_dinv      <<<nbN, TPB, 0, stream>>>(dinv, N);
    k_scan1     <<<nbScan, SCANB, 0, stream>>>(counts, row_start, partials, N);
    k_scan2     <<<1, 64, 0, stream>>>(partials, nbScan);
    k_scan3     <<<nbScan, SCANB, 0, stream>>>(row_start, partials, cursor, N);
    k_fill      <<<nbE, TPB, 0, stream>>>(src, dst, ew, dinv, cursor, srcs, norms, E, N);

    // ---- layer 1: h = x@W1; d_out = aggregate(h) + b1 (ReLU deferred) ----
    k_gemm<0>      <<<gemm_grid, TPB, 0, stream>>>(x, W1, h, N);
    k_aggregate<0> <<<nbAgg, TPB, 0, stream>>>(h, row_start, counts, srcs, norms,
                                               dinv, b1, out, N);

    // ---- layer 2: h = relu(d_out)@W2; d_out = relu(aggregate(h) + b2) ----
    k_gemm<1>      <<<gemm_grid, TPB, 0, stream>>>(out, W2, h, N);
    k_aggregate<1> <<<nbAgg, TPB, 0, stream>>>(h, row_start, counts, srcs, norms,
                                               dinv, b2, out, N);
}

// Round 3
// 398.806 us; speedup vs baseline: 5.7212x; 1.0154x over previous
//
#include <hip/hip_runtime.h>
#include <math.h>

// GCN 2-layer forward on MI355X — round 3: register-blocked fp32 GEMM
// (8 rows x 4 cols per thread -> FMA-bound instead of LDS-issue-bound).
#define CH   128
#define CH4  32          // CH / 4 (float4 granularity)
#define TPB  256
#define SCANB 1024

// ---------------------------------------------------------------------------
// init: deg = 1 (self-loop), counts = 0
// ---------------------------------------------------------------------------
__global__ void k_init(float* __restrict__ deg, int* __restrict__ counts, int n) {
    int i = blockIdx.x * blockDim.x + threadIdx.x;
    if (i < n) { deg[i] = 1.0f; counts[i] = 0; }
}

// per-edge: deg[dst] += ew; counts[dst] += 1
__global__ void k_edge_pass1(const int* __restrict__ dst, const float* __restrict__ ew,
                             float* __restrict__ deg, int* __restrict__ counts,
                             int E, int n) {
    int e = blockIdx.x * blockDim.x + threadIdx.x;
    if (e < E) {
        int d = dst[e];
        if ((unsigned)d < (unsigned)n) {
            unsafeAtomicAdd(&deg[d], ew[e]);
            atomicAdd(&counts[d], 1);
        }
    }
}

__global__ void k_dinv(float* __restrict__ deg, int n) {
    int i = blockIdx.x * blockDim.x + threadIdx.x;
    if (i < n) {
        float d = deg[i];
        deg[i] = (d > 0.0f) ? rsqrtf(d) : 0.0f;  // in-place: deg -> dinv
    }
}

// ---------------------------------------------------------------------------
// 3-pass exclusive prefix sum over counts[n] -> row_start[n]
// ---------------------------------------------------------------------------
__global__ __launch_bounds__(SCANB)
void k_scan1(const int* __restrict__ counts, int* __restrict__ row_start,
             int* __restrict__ partials, int n) {
    __shared__ int s[SCANB];
    int gid = blockIdx.x * SCANB + threadIdx.x;
    int v = (gid < n) ? counts[gid] : 0;
    s[threadIdx.x] = v;
    __syncthreads();
    for (int off = 1; off < SCANB; off <<= 1) {
        int t = (threadIdx.x >= off) ? s[threadIdx.x - off] : 0;
        __syncthreads();
        s[threadIdx.x] += t;
        __syncthreads();
    }
    if (gid < n) row_start[gid] = s[threadIdx.x] - v;   // exclusive within block
    if (threadIdx.x == SCANB - 1) partials[blockIdx.x] = s[SCANB - 1];
}

__global__ __launch_bounds__(64)
void k_scan2(int* __restrict__ partials, int nb) {     // nb <= 64
    __shared__ int s[64];
    int v = (threadIdx.x < nb) ? partials[threadIdx.x] : 0;
    s[threadIdx.x] = v;
    __syncthreads();
    for (int off = 1; off < 64; off <<= 1) {
        int t = (threadIdx.x >= off) ? s[threadIdx.x - off] : 0;
        __syncthreads();
        s[threadIdx.x] += t;
        __syncthreads();
    }
    if (threadIdx.x < nb) partials[threadIdx.x] = s[threadIdx.x] - v;  // exclusive
}

__global__ __launch_bounds__(SCANB)
void k_scan3(int* __restrict__ row_start, const int* __restrict__ partials,
             int* __restrict__ cursor, int n) {
    int gid = blockIdx.x * SCANB + threadIdx.x;
    if (gid < n) {
        int v = row_start[gid] + partials[blockIdx.x];
        row_start[gid] = v;
        cursor[gid] = v;
    }
}

// per-edge: pos = cursor[dst]++; srcs[pos] = src; norms[pos] = full edge norm
__global__ void k_fill(const int* __restrict__ src, const int* __restrict__ dst,
                       const float* __restrict__ ew, const float* __restrict__ dinv,
                       int* __restrict__ cursor, int* __restrict__ srcs,
                       float* __restrict__ norms, int E, int n) {
    int e = blockIdx.x * blockDim.x + threadIdx.x;
    if (e >= E) return;
    int s = src[e], d = dst[e];
    if ((unsigned)s >= (unsigned)n || (unsigned)d >= (unsigned)n) return;
    int pos = atomicAdd(&cursor[d], 1);
    srcs[pos] = s;
    norms[pos] = dinv[s] * ew[e] * dinv[d];
}

// ---------------------------------------------------------------------------
// H = (relu?)(X) @ W — fp32 register-blocked GEMM, W (64 KB) in LDS.
// 256 threads: tx = col group (4 cols), ty = row group; 8 rows/thread.
// Block covers 64 rows. Per k4 iter: 4 LDS b128 (shared over 8 rows),
// 8 broadcast x loads, 128 FMAs -> VALU-bound.
// ---------------------------------------------------------------------------
template<int RELU_IN>
__global__ __launch_bounds__(TPB, 2)
void k_gemm(const float* __restrict__ X, const float* __restrict__ W,
            float* __restrict__ H, int n) {
    __shared__ float sW[CH * CH];
    float4* sW4 = (float4*)sW;
    const float4* W4 = (const float4*)W;
    for (int i = threadIdx.x; i < CH * CH4; i += TPB) sW4[i] = W4[i];
    __syncthreads();

    const int tx = threadIdx.x & 31;       // col group
    const int ty = threadIdx.x >> 5;       // 0..7
    const int row0 = blockIdx.x * 64 + ty * 8;
    if (row0 >= n) return;                 // no barriers after this point

    const float4* X4 = (const float4*)X;
    const float4* xp[8];
    #pragma unroll
    for (int i = 0; i < 8; ++i) {
        int r = row0 + i;
        if (r > n - 1) r = n - 1;          // clamp loads, guard stores below
        xp[i] = X4 + (size_t)r * CH4;
    }

    float4 acc[8];
    #pragma unroll
    for (int i = 0; i < 8; ++i) acc[i] = make_float4(0.f, 0.f, 0.f, 0.f);

    #pragma unroll 2
    for (int k4 = 0; k4 < CH4; ++k4) {
        float4 w0 = sW4[(k4 * 4 + 0) * CH4 + tx];
        float4 w1 = sW4[(k4 * 4 + 1) * CH4 + tx];
        float4 w2 = sW4[(k4 * 4 + 2) * CH4 + tx];
        float4 w3 = sW4[(k4 * 4 + 3) * CH4 + tx];
        #pragma unroll
        for (int i = 0; i < 8; ++i) {
            float4 xv = xp[i][k4];         // 32-lane broadcast (L1)
            if (RELU_IN) {
                xv.x = fmaxf(xv.x, 0.f); xv.y = fmaxf(xv.y, 0.f);
                xv.z = fmaxf(xv.z, 0.f); xv.w = fmaxf(xv.w, 0.f);
            }
            acc[i].x += xv.x * w0.x + xv.y * w1.x + xv.z * w2.x + xv.w * w3.x;
            acc[i].y += xv.x * w0.y + xv.y * w1.y + xv.z * w2.y + xv.w * w3.y;
            acc[i].z += xv.x * w0.z + xv.y * w1.z + xv.z * w2.z + xv.w * w3.z;
            acc[i].w += xv.x * w0.w + xv.y * w1.w + xv.z * w2.w + xv.w * w3.w;
        }
    }

    #pragma unroll
    for (int i = 0; i < 8; ++i) {
        int r = row0 + i;
        if (r < n) ((float4*)H)[(size_t)r * CH4 + tx] = acc[i];
    }
}

// ---------------------------------------------------------------------------
// CSR aggregate: out[i] = (relu?)( h[i]*dinv[i]^2 + bias + sum_j h[srcs[j]]*norms[j] )
// 32 lanes per node (4 ch each), 8 nodes per 256-thread block.
// ---------------------------------------------------------------------------
template<int RELU_OUT>
__global__ __launch_bounds__(TPB)
void k_aggregate(const float* __restrict__ h, const int* __restrict__ row_start,
                 const int* __restrict__ counts, const int* __restrict__ srcs,
                 const float* __restrict__ norms, const float* __restrict__ dinv,
                 const float* __restrict__ bias, float* __restrict__ out, int n) {
    int t = blockIdx.x * blockDim.x + threadIdx.x;
    int node = t >> 5;
    if (node >= n) return;
    int tx = t & 31;

    float di = dinv[node];
    float sc = di * di;
    float4 b  = ((const float4*)bias)[tx];
    float4 hv = ((const float4*)h)[(size_t)node * CH4 + tx];
    float4 acc = make_float4(hv.x * sc + b.x, hv.y * sc + b.y,
                             hv.z * sc + b.z, hv.w * sc + b.w);

    int start = row_start[node];
    int end   = start + counts[node];
    for (int j = start; j < end; ++j) {
        int s     = srcs[j];    // uniform across the 32 lanes -> broadcast
        float nrm = norms[j];
        float4 g = ((const float4*)h)[(size_t)s * CH4 + tx];
        acc.x += g.x * nrm; acc.y += g.y * nrm;
        acc.z += g.z * nrm; acc.w += g.w * nrm;
    }
    if (RELU_OUT) {
        acc.x = fmaxf(acc.x, 0.f); acc.y = fmaxf(acc.y, 0.f);
        acc.z = fmaxf(acc.z, 0.f); acc.w = fmaxf(acc.w, 0.f);
    }
    ((float4*)out)[(size_t)node * CH4 + tx] = acc;
}

// ---------------------------------------------------------------------------
extern "C" void kernel_launch(void* const* d_in, const int* in_sizes, int n_in,
                              void* d_out, int out_size, void* d_ws, size_t ws_size,
                              hipStream_t stream) {
    const float* x  = (const float*)d_in[0];   // [N,128]
    const int*   ei = (const int*)d_in[1];     // [2,E]
    const float* ew = (const float*)d_in[2];   // [E]
    const float* W1 = (const float*)d_in[3];
    const float* b1 = (const float*)d_in[4];
    const float* W2 = (const float*)d_in[5];
    const float* b2 = (const float*)d_in[6];
    float* out = (float*)d_out;                // [N,128]

    const int N = in_sizes[0] / CH;
    const int E = in_sizes[2];
    const int* src = ei;
    const int* dst = ei + E;

    // workspace layout (all 16B-aligned)
    size_t Np = ((size_t)N + 255) & ~(size_t)255;
    float* ws        = (float*)d_ws;
    float* dinv      = ws;                          // N floats
    float* h         = dinv + Np;                   // N*CH floats
    int*   counts    = (int*)(h + (size_t)N * CH);  // N ints
    int*   row_start = counts + Np;                 // N ints
    int*   cursor    = row_start + Np;              // N ints
    int*   partials  = cursor + Np;                 // 64 ints
    int*   srcs      = partials + 64;               // E ints
    float* norms     = (float*)(srcs + E);          // E floats

    const int nbN    = (N + TPB - 1) / TPB;
    const int nbE    = (E + TPB - 1) / TPB;
    const int nbAgg  = (int)(((size_t)N * 32 + TPB - 1) / TPB);
    const int nbScan = (N + SCANB - 1) / SCANB;     // 49 <= 64
    const int nbGemm = (N + 63) / 64;               // 782 tiles

    // ---- CSR build + normalization (shared by both layers) ----
    k_init      <<<nbN, TPB, 0, stream>>>(dinv, counts, N);
    k_edge_pass1<<<nbE, TPB, 0, stream>>>(dst, ew, dinv, counts, E, N);
    k_dinv      <<<nbN, TPB, 0, stream>>>(dinv, N);
    k_scan1     <<<nbScan, SCANB, 0, stream>>>(counts, row_start, partials, N);
    k_scan2     <<<1, 64, 0, stream>>>(partials, nbScan);
    k_scan3     <<<nbScan, SCANB, 0, stream>>>(row_start, partials, cursor, N);
    k_fill      <<<nbE, TPB, 0, stream>>>(src, dst, ew, dinv, cursor, srcs, norms, E, N);

    // ---- layer 1: h = x@W1; d_out = aggregate(h) + b1 (ReLU deferred) ----
    k_gemm<0>      <<<nbGemm, TPB, 0, stream>>>(x, W1, h, N);
    k_aggregate<0> <<<nbAgg, TPB, 0, stream>>>(h, row_start, counts, srcs, norms,
                                               dinv, b1, out, N);

    // ---- layer 2: h = relu(d_out)@W2; d_out = relu(aggregate(h) + b2) ----
    k_gemm<1>      <<<nbGemm, TPB, 0, stream>>>(out, W2, h, N);
    k_aggregate<1> <<<nbAgg, TPB, 0, stream>>>(h, row_start, counts, srcs, norms,
                                               dinv, b2, out, N);
}

// Round 4
// 370.127 us; speedup vs baseline: 6.1645x; 1.0775x over previous
//
#include <hip/hip_runtime.h>
#include <math.h>

// GCN 2-layer forward on MI355X — round 4:
//  * GEMM: 32 KB W-tile (col-split) -> 2x occupancy; explicit x prefetch.
//  * Aggregate: packed (src,norm) int2 + 4x unrolled gather for ILP.
#define CH   128
#define CH4  32          // CH / 4 (float4 granularity)
#define TPB  256
#define SCANB 1024

// ---------------------------------------------------------------------------
// init: deg = 1 (self-loop), counts = 0
// ---------------------------------------------------------------------------
__global__ void k_init(float* __restrict__ deg, int* __restrict__ counts, int n) {
    int i = blockIdx.x * blockDim.x + threadIdx.x;
    if (i < n) { deg[i] = 1.0f; counts[i] = 0; }
}

// per-edge: deg[dst] += ew; counts[dst] += 1
__global__ void k_edge_pass1(const int* __restrict__ dst, const float* __restrict__ ew,
                             float* __restrict__ deg, int* __restrict__ counts,
                             int E, int n) {
    int e = blockIdx.x * blockDim.x + threadIdx.x;
    if (e < E) {
        int d = dst[e];
        if ((unsigned)d < (unsigned)n) {
            unsafeAtomicAdd(&deg[d], ew[e]);
            atomicAdd(&counts[d], 1);
        }
    }
}

__global__ void k_dinv(float* __restrict__ deg, int n) {
    int i = blockIdx.x * blockDim.x + threadIdx.x;
    if (i < n) {
        float d = deg[i];
        deg[i] = (d > 0.0f) ? rsqrtf(d) : 0.0f;  // in-place: deg -> dinv
    }
}

// ---------------------------------------------------------------------------
// 3-pass exclusive prefix sum over counts[n] -> row_start[n]
// ---------------------------------------------------------------------------
__global__ __launch_bounds__(SCANB)
void k_scan1(const int* __restrict__ counts, int* __restrict__ row_start,
             int* __restrict__ partials, int n) {
    __shared__ int s[SCANB];
    int gid = blockIdx.x * SCANB + threadIdx.x;
    int v = (gid < n) ? counts[gid] : 0;
    s[threadIdx.x] = v;
    __syncthreads();
    for (int off = 1; off < SCANB; off <<= 1) {
        int t = (threadIdx.x >= off) ? s[threadIdx.x - off] : 0;
        __syncthreads();
        s[threadIdx.x] += t;
        __syncthreads();
    }
    if (gid < n) row_start[gid] = s[threadIdx.x] - v;   // exclusive within block
    if (threadIdx.x == SCANB - 1) partials[blockIdx.x] = s[SCANB - 1];
}

__global__ __launch_bounds__(64)
void k_scan2(int* __restrict__ partials, int nb) {     // nb <= 64
    __shared__ int s[64];
    int v = (threadIdx.x < nb) ? partials[threadIdx.x] : 0;
    s[threadIdx.x] = v;
    __syncthreads();
    for (int off = 1; off < 64; off <<= 1) {
        int t = (threadIdx.x >= off) ? s[threadIdx.x - off] : 0;
        __syncthreads();
        s[threadIdx.x] += t;
        __syncthreads();
    }
    if (threadIdx.x < nb) partials[threadIdx.x] = s[threadIdx.x] - v;  // exclusive
}

__global__ __launch_bounds__(SCANB)
void k_scan3(int* __restrict__ row_start, const int* __restrict__ partials,
             int* __restrict__ cursor, int n) {
    int gid = blockIdx.x * SCANB + threadIdx.x;
    if (gid < n) {
        int v = row_start[gid] + partials[blockIdx.x];
        row_start[gid] = v;
        cursor[gid] = v;
    }
}

// per-edge: pos = cursor[dst]++; edges[pos] = {src, norm}
__global__ void k_fill(const int* __restrict__ src, const int* __restrict__ dst,
                       const float* __restrict__ ew, const float* __restrict__ dinv,
                       int* __restrict__ cursor, int2* __restrict__ edges,
                       int E, int n) {
    int e = blockIdx.x * blockDim.x + threadIdx.x;
    if (e >= E) return;
    int s = src[e], d = dst[e];
    if ((unsigned)s >= (unsigned)n || (unsigned)d >= (unsigned)n) return;
    int pos = atomicAdd(&cursor[d], 1);
    edges[pos] = make_int2(s, __float_as_int(dinv[s] * ew[e] * dinv[d]));
}

// ---------------------------------------------------------------------------
// H = (relu?)(X) @ W — fp32 register-blocked GEMM.
// Grid: (ceil(n/128), 2). Block computes 128 rows x 64 cols.
// W tile for this col half: 128 k x 64 cols = 32 KB LDS -> higher occupancy.
// 256 threads: tx = col group (4 cols, 16 groups), ty = row group (8 rows).
// Explicit prefetch of next-k4 x values hides L2 latency under the FMA block.
// ---------------------------------------------------------------------------
template<int RELU_IN>
__global__ __launch_bounds__(TPB, 3)
void k_gemm(const float* __restrict__ X, const float* __restrict__ W,
            float* __restrict__ H, int n) {
    __shared__ float sW[CH * 64];          // 32 KB
    float4* sW4 = (float4*)sW;             // [128][16] float4
    const float4* W4 = (const float4*)W;   // [128][32] float4
    const int colh = blockIdx.y;           // 0 or 1
    for (int i = threadIdx.x; i < CH * 16; i += TPB) {
        int row = i >> 4, cg = i & 15;
        sW4[i] = W4[row * CH4 + colh * 16 + cg];
    }
    __syncthreads();

    const int tx = threadIdx.x & 15;       // col group within half (4 cols)
    const int ty = threadIdx.x >> 4;       // 0..15
    const int row0 = blockIdx.x * 128 + ty * 8;
    if (row0 >= n) return;                 // after the only barrier: safe

    const float4* X4 = (const float4*)X;
    const float4* xp[8];
    #pragma unroll
    for (int i = 0; i < 8; ++i) {
        int r = row0 + i;
        if (r > n - 1) r = n - 1;          // clamp loads; stores guarded below
        xp[i] = X4 + (size_t)r * CH4;
    }

    float4 acc[8];
    #pragma unroll
    for (int i = 0; i < 8; ++i) acc[i] = make_float4(0.f, 0.f, 0.f, 0.f);

    float4 xcur[8];
    #pragma unroll
    for (int i = 0; i < 8; ++i) xcur[i] = xp[i][0];

    #pragma unroll 2
    for (int k4 = 0; k4 < CH4; ++k4) {
        float4 xnxt[8];
        const int kn = (k4 + 1) & (CH4 - 1);   // last iter reloads k=0 (unused)
        #pragma unroll
        for (int i = 0; i < 8; ++i) xnxt[i] = xp[i][kn];

        float4 w0 = sW4[(k4 * 4 + 0) * 16 + tx];
        float4 w1 = sW4[(k4 * 4 + 1) * 16 + tx];
        float4 w2 = sW4[(k4 * 4 + 2) * 16 + tx];
        float4 w3 = sW4[(k4 * 4 + 3) * 16 + tx];

        #pragma unroll
        for (int i = 0; i < 8; ++i) {
            float4 xv = xcur[i];
            if (RELU_IN) {
                xv.x = fmaxf(xv.x, 0.f); xv.y = fmaxf(xv.y, 0.f);
                xv.z = fmaxf(xv.z, 0.f); xv.w = fmaxf(xv.w, 0.f);
            }
            acc[i].x += xv.x * w0.x + xv.y * w1.x + xv.z * w2.x + xv.w * w3.x;
            acc[i].y += xv.x * w0.y + xv.y * w1.y + xv.z * w2.y + xv.w * w3.y;
            acc[i].z += xv.x * w0.z + xv.y * w1.z + xv.z * w2.z + xv.w * w3.z;
            acc[i].w += xv.x * w0.w + xv.y * w1.w + xv.z * w2.w + xv.w * w3.w;
        }
        #pragma unroll
        for (int i = 0; i < 8; ++i) xcur[i] = xnxt[i];
    }

    #pragma unroll
    for (int i = 0; i < 8; ++i) {
        int r = row0 + i;
        if (r < n) ((float4*)H)[(size_t)r * CH4 + colh * 16 + tx] = acc[i];
    }
}

// ---------------------------------------------------------------------------
// CSR aggregate: out[i] = (relu?)( h[i]*dinv[i]^2 + bias + sum_j h[s_j]*nrm_j )
// 32 lanes per node (4 ch each), 8 nodes per 256-thread block.
// Edge loop unrolled x4 -> 4 outstanding row gathers per chain.
// ---------------------------------------------------------------------------
template<int RELU_OUT>
__global__ __launch_bounds__(TPB)
void k_aggregate(const float* __restrict__ h, const int* __restrict__ row_start,
                 const int* __restrict__ counts, const int2* __restrict__ edges,
                 const float* __restrict__ dinv, const float* __restrict__ bias,
                 float* __restrict__ out, int n) {
    int t = blockIdx.x * blockDim.x + threadIdx.x;
    int node = t >> 5;
    if (node >= n) return;
    int tx = t & 31;

    const float4* h4 = (const float4*)h;
    float di = dinv[node];
    float sc = di * di;
    float4 b  = ((const float4*)bias)[tx];
    float4 hv = h4[(size_t)node * CH4 + tx];
    float4 acc = make_float4(hv.x * sc + b.x, hv.y * sc + b.y,
                             hv.z * sc + b.z, hv.w * sc + b.w);

    int j   = row_start[node];
    int end = j + counts[node];

    for (; j + 4 <= end; j += 4) {
        int2 e0 = edges[j];     int2 e1 = edges[j + 1];
        int2 e2 = edges[j + 2]; int2 e3 = edges[j + 3];
        float4 g0 = h4[(size_t)e0.x * CH4 + tx];
        float4 g1 = h4[(size_t)e1.x * CH4 + tx];
        float4 g2 = h4[(size_t)e2.x * CH4 + tx];
        float4 g3 = h4[(size_t)e3.x * CH4 + tx];
        float n0 = __int_as_float(e0.y), n1 = __int_as_float(e1.y);
        float n2 = __int_as_float(e2.y), n3 = __int_as_float(e3.y);
        acc.x += g0.x * n0 + g1.x * n1 + g2.x * n2 + g3.x * n3;
        acc.y += g0.y * n0 + g1.y * n1 + g2.y * n2 + g3.y * n3;
        acc.z += g0.z * n0 + g1.z * n1 + g2.z * n2 + g3.z * n3;
        acc.w += g0.w * n0 + g1.w * n1 + g2.w * n2 + g3.w * n3;
    }
    for (; j < end; ++j) {
        int2 e0 = edges[j];
        float nrm = __int_as_float(e0.y);
        float4 g = h4[(size_t)e0.x * CH4 + tx];
        acc.x += g.x * nrm; acc.y += g.y * nrm;
        acc.z += g.z * nrm; acc.w += g.w * nrm;
    }
    if (RELU_OUT) {
        acc.x = fmaxf(acc.x, 0.f); acc.y = fmaxf(acc.y, 0.f);
        acc.z = fmaxf(acc.z, 0.f); acc.w = fmaxf(acc.w, 0.f);
    }
    ((float4*)out)[(size_t)node * CH4 + tx] = acc;
}

// ---------------------------------------------------------------------------
extern "C" void kernel_launch(void* const* d_in, const int* in_sizes, int n_in,
                              void* d_out, int out_size, void* d_ws, size_t ws_size,
                              hipStream_t stream) {
    const float* x  = (const float*)d_in[0];   // [N,128]
    const int*   ei = (const int*)d_in[1];     // [2,E]
    const float* ew = (const float*)d_in[2];   // [E]
    const float* W1 = (const float*)d_in[3];
    const float* b1 = (const float*)d_in[4];
    const float* W2 = (const float*)d_in[5];
    const float* b2 = (const float*)d_in[6];
    float* out = (float*)d_out;                // [N,128]

    const int N = in_sizes[0] / CH;
    const int E = in_sizes[2];
    const int* src = ei;
    const int* dst = ei + E;

    // workspace layout (all 16B-aligned)
    size_t Np = ((size_t)N + 255) & ~(size_t)255;
    float* ws        = (float*)d_ws;
    float* dinv      = ws;                          // N floats
    float* h         = dinv + Np;                   // N*CH floats
    int*   counts    = (int*)(h + (size_t)N * CH);  // N ints
    int*   row_start = counts + Np;                 // N ints
    int*   cursor    = row_start + Np;              // N ints
    int*   partials  = cursor + Np;                 // 64 ints
    int2*  edges     = (int2*)(partials + 64);      // E int2

    const int nbN    = (N + TPB - 1) / TPB;
    const int nbE    = (E + TPB - 1) / TPB;
    const int nbAgg  = (int)(((size_t)N * 32 + TPB - 1) / TPB);
    const int nbScan = (N + SCANB - 1) / SCANB;     // 49 <= 64
    const dim3 gGemm((N + 127) / 128, 2);           // 391 x 2 blocks

    // ---- CSR build + normalization (shared by both layers) ----
    k_init      <<<nbN, TPB, 0, stream>>>(dinv, counts, N);
    k_edge_pass1<<<nbE, TPB, 0, stream>>>(dst, ew, dinv, counts, E, N);
    k_dinv      <<<nbN, TPB, 0, stream>>>(dinv, N);
    k_scan1     <<<nbScan, SCANB, 0, stream>>>(counts, row_start, partials, N);
    k_scan2     <<<1, 64, 0, stream>>>(partials, nbScan);
    k_scan3     <<<nbScan, SCANB, 0, stream>>>(row_start, partials, cursor, N);
    k_fill      <<<nbE, TPB, 0, stream>>>(src, dst, ew, dinv, cursor, edges, E, N);

    // ---- layer 1: h = x@W1; d_out = aggregate(h) + b1 (ReLU deferred) ----
    k_gemm<0>      <<<gGemm, TPB, 0, stream>>>(x, W1, h, N);
    k_aggregate<0> <<<nbAgg, TPB, 0, stream>>>(h, row_start, counts, edges,
                                               dinv, b1, out, N);

    // ---- layer 2: h = relu(d_out)@W2; d_out = relu(aggregate(h) + b2) ----
    k_gemm<1>      <<<gGemm, TPB, 0, stream>>>(out, W2, h, N);
    k_aggregate<1> <<<nbAgg, TPB, 0, stream>>>(h, row_start, counts, edges,
                                               dinv, b2, out, N);
}

// Round 5
// 335.866 us; speedup vs baseline: 6.7933x; 1.1020x over previous
//
#include <hip/hip_runtime.h>
#include <math.h>

// GCN 2-layer forward on MI355X — round 5: bf16 MFMA GEMM with 3-term
// Markidis split (fp32-accurate), W pre-split into B-fragments in LDS.
#define CH   128
#define CH4  32          // CH / 4 (float4 granularity)
#define TPB  256
#define SCANB 1024

typedef __attribute__((ext_vector_type(8))) short short8;   // 8 bf16 (4 VGPRs)
typedef __attribute__((ext_vector_type(4))) float floatx4;  // MFMA acc

// round-to-nearest-even fp32 -> bf16 (as bit-pattern in short)
static __device__ __forceinline__ short f2bf(float f) {
    unsigned u = __float_as_uint(f);
    unsigned r = (u + 0x7fffu + ((u >> 16) & 1u)) >> 16;
    return (short)r;
}
static __device__ __forceinline__ float bf2f(short s) {
    return __uint_as_float(((unsigned)(unsigned short)s) << 16);
}

// ---------------------------------------------------------------------------
// init: deg = 1 (self-loop), counts = 0
// ---------------------------------------------------------------------------
__global__ void k_init(float* __restrict__ deg, int* __restrict__ counts, int n) {
    int i = blockIdx.x * blockDim.x + threadIdx.x;
    if (i < n) { deg[i] = 1.0f; counts[i] = 0; }
}

// per-edge: deg[dst] += ew; counts[dst] += 1
__global__ void k_edge_pass1(const int* __restrict__ dst, const float* __restrict__ ew,
                             float* __restrict__ deg, int* __restrict__ counts,
                             int E, int n) {
    int e = blockIdx.x * blockDim.x + threadIdx.x;
    if (e < E) {
        int d = dst[e];
        if ((unsigned)d < (unsigned)n) {
            unsafeAtomicAdd(&deg[d], ew[e]);
            atomicAdd(&counts[d], 1);
        }
    }
}

// ---------------------------------------------------------------------------
// scan pass 1 (+ fused deg -> dinv conversion)
// ---------------------------------------------------------------------------
__global__ __launch_bounds__(SCANB)
void k_scan1(const int* __restrict__ counts, int* __restrict__ row_start,
             int* __restrict__ partials, float* __restrict__ deg, int n) {
    __shared__ int s[SCANB];
    int gid = blockIdx.x * SCANB + threadIdx.x;
    int v = (gid < n) ? counts[gid] : 0;
    s[threadIdx.x] = v;
    __syncthreads();
    for (int off = 1; off < SCANB; off <<= 1) {
        int t = (threadIdx.x >= off) ? s[threadIdx.x - off] : 0;
        __syncthreads();
        s[threadIdx.x] += t;
        __syncthreads();
    }
    if (gid < n) {
        row_start[gid] = s[threadIdx.x] - v;   // exclusive within block
        float d = deg[gid];
        deg[gid] = (d > 0.0f) ? rsqrtf(d) : 0.0f;   // deg -> dinv in place
    }
    if (threadIdx.x == SCANB - 1) partials[blockIdx.x] = s[SCANB - 1];
}

__global__ __launch_bounds__(64)
void k_scan2(int* __restrict__ partials, int nb) {     // nb <= 64
    __shared__ int s[64];
    int v = (threadIdx.x < nb) ? partials[threadIdx.x] : 0;
    s[threadIdx.x] = v;
    __syncthreads();
    for (int off = 1; off < 64; off <<= 1) {
        int t = (threadIdx.x >= off) ? s[threadIdx.x - off] : 0;
        __syncthreads();
        s[threadIdx.x] += t;
        __syncthreads();
    }
    if (threadIdx.x < nb) partials[threadIdx.x] = s[threadIdx.x] - v;  // exclusive
}

__global__ __launch_bounds__(SCANB)
void k_scan3(int* __restrict__ row_start, const int* __restrict__ partials,
             int* __restrict__ cursor, int n) {
    int gid = blockIdx.x * SCANB + threadIdx.x;
    if (gid < n) {
        int v = row_start[gid] + partials[blockIdx.x];
        row_start[gid] = v;
        cursor[gid] = v;
    }
}

// per-edge: pos = cursor[dst]++; edges[pos] = {src, norm}
__global__ void k_fill(const int* __restrict__ src, const int* __restrict__ dst,
                       const float* __restrict__ ew, const float* __restrict__ dinv,
                       int* __restrict__ cursor, int2* __restrict__ edges,
                       int E, int n) {
    int e = blockIdx.x * blockDim.x + threadIdx.x;
    if (e >= E) return;
    int s = src[e], d = dst[e];
    if ((unsigned)s >= (unsigned)n || (unsigned)d >= (unsigned)n) return;
    int pos = atomicAdd(&cursor[d], 1);
    edges[pos] = make_int2(s, __float_as_int(dinv[s] * ew[e] * dinv[d]));
}

// ---------------------------------------------------------------------------
// H = (relu?)(X) @ W — bf16 MFMA (16x16x32) with 3-term hi/lo split:
//   x*w ~= xh*wh + xl*wh + xh*wl   (fp32-accurate; xl*wl ~ 2^-18 dropped)
// Grid: (ceil(n/64), 2). Block = 4 waves; wave w owns rows [blk*64+w*16, +16)
// and all 64 cols of its col-half. W hi/lo staged as B-fragments in LDS.
// Frag layouts (m89/m91/m120-verified):
//   A: m = lane&15, k = (lane>>4)*8 + j
//   B: n = lane&15, k = (lane>>4)*8 + j
//   D: col = lane&15, row = (lane>>4)*4 + reg
// ---------------------------------------------------------------------------
template<int RELU_IN>
__global__ __launch_bounds__(TPB, 4)
void k_gemm(const float* __restrict__ X, const float* __restrict__ W,
            float* __restrict__ H, int n) {
    // sW[h][kt][ns][lane][j]: h=0 hi, h=1 lo; kt = k-tile (K=32), ns = 16-col stripe
    __shared__ __align__(16) short sW[2][4][4][64][8];   // 32 KB
    const int tid  = threadIdx.x;
    const int colh = blockIdx.y;                          // 0 or 1

    // stage W for this 64-col half, pre-split into bf16 hi/lo B-fragments
    for (int i = tid; i < 128 * 64; i += TPB) {
        int k  = i >> 6;
        int nn = i & 63;
        float w = W[k * CH + colh * 64 + nn];             // coalesced over nn
        short hi = f2bf(w);
        short lo = f2bf(w - bf2f(hi));
        int kt = k >> 5, q = (k & 31) >> 3, j = k & 7;
        int ns = nn >> 4, ln = q * 16 + (nn & 15);
        sW[0][kt][ns][ln][j] = hi;
        sW[1][kt][ns][ln][j] = lo;
    }
    __syncthreads();

    const int lane = tid & 63;
    const int wv   = tid >> 6;          // wave 0..3
    const int q    = lane >> 4;         // quad 0..3
    const int m    = lane & 15;
    const int row0 = blockIdx.x * 64 + wv * 16;

    int rrow = row0 + m;
    if (rrow > n - 1) rrow = n - 1;     // clamp loads; stores guarded below

    // this lane's A data: x[rrow][kt*32 + q*8 .. +7] for kt = 0..3 (8 fp32 each)
    const float4* xr = (const float4*)(X + (size_t)rrow * CH);
    float4 xa[4][2];
    #pragma unroll
    for (int kt = 0; kt < 4; ++kt) {
        xa[kt][0] = xr[kt * 8 + q * 2 + 0];
        xa[kt][1] = xr[kt * 8 + q * 2 + 1];
    }

    floatx4 acc[4];
    #pragma unroll
    for (int ns = 0; ns < 4; ++ns) acc[ns] = (floatx4){0.f, 0.f, 0.f, 0.f};

    #pragma unroll
    for (int kt = 0; kt < 4; ++kt) {
        float xf[8] = { xa[kt][0].x, xa[kt][0].y, xa[kt][0].z, xa[kt][0].w,
                        xa[kt][1].x, xa[kt][1].y, xa[kt][1].z, xa[kt][1].w };
        short8 ah, al;
        #pragma unroll
        for (int j = 0; j < 8; ++j) {
            float v = xf[j];
            if (RELU_IN) v = fmaxf(v, 0.f);
            short h = f2bf(v);
            ah[j] = h;
            al[j] = f2bf(v - bf2f(h));
        }
        #pragma unroll
        for (int ns = 0; ns < 4; ++ns) {
            short8 bh = *(const short8*)&sW[0][kt][ns][lane][0];
            short8 bl = *(const short8*)&sW[1][kt][ns][lane][0];
            acc[ns] = __builtin_amdgcn_mfma_f32_16x16x32_bf16(ah, bh, acc[ns], 0, 0, 0);
            acc[ns] = __builtin_amdgcn_mfma_f32_16x16x32_bf16(al, bh, acc[ns], 0, 0, 0);
            acc[ns] = __builtin_amdgcn_mfma_f32_16x16x32_bf16(ah, bl, acc[ns], 0, 0, 0);
        }
    }

    // D: col = m, row = q*4 + reg
    #pragma unroll
    for (int ns = 0; ns < 4; ++ns) {
        #pragma unroll
        for (int reg = 0; reg < 4; ++reg) {
            int r = row0 + q * 4 + reg;
            if (r < n)
                H[(size_t)r * CH + colh * 64 + ns * 16 + m] = acc[ns][reg];
        }
    }
}

// ---------------------------------------------------------------------------
// CSR aggregate: out[i] = (relu?)( h[i]*dinv[i]^2 + bias + sum_j h[s_j]*nrm_j )
// 32 lanes per node (4 ch each); edge loop unrolled x4 for gather ILP.
// ---------------------------------------------------------------------------
template<int RELU_OUT>
__global__ __launch_bounds__(TPB)
void k_aggregate(const float* __restrict__ h, const int* __restrict__ row_start,
                 const int* __restrict__ counts, const int2* __restrict__ edges,
                 const float* __restrict__ dinv, const float* __restrict__ bias,
                 float* __restrict__ out, int n) {
    int t = blockIdx.x * blockDim.x + threadIdx.x;
    int node = t >> 5;
    if (node >= n) return;
    int tx = t & 31;

    const float4* h4 = (const float4*)h;
    float di = dinv[node];
    float sc = di * di;
    float4 b  = ((const float4*)bias)[tx];
    float4 hv = h4[(size_t)node * CH4 + tx];
    float4 acc = make_float4(hv.x * sc + b.x, hv.y * sc + b.y,
                             hv.z * sc + b.z, hv.w * sc + b.w);

    int j   = row_start[node];
    int end = j + counts[node];

    for (; j + 4 <= end; j += 4) {
        int2 e0 = edges[j];     int2 e1 = edges[j + 1];
        int2 e2 = edges[j + 2]; int2 e3 = edges[j + 3];
        float4 g0 = h4[(size_t)e0.x * CH4 + tx];
        float4 g1 = h4[(size_t)e1.x * CH4 + tx];
        float4 g2 = h4[(size_t)e2.x * CH4 + tx];
        float4 g3 = h4[(size_t)e3.x * CH4 + tx];
        float n0 = __int_as_float(e0.y), n1 = __int_as_float(e1.y);
        float n2 = __int_as_float(e2.y), n3 = __int_as_float(e3.y);
        acc.x += g0.x * n0 + g1.x * n1 + g2.x * n2 + g3.x * n3;
        acc.y += g0.y * n0 + g1.y * n1 + g2.y * n2 + g3.y * n3;
        acc.z += g0.z * n0 + g1.z * n1 + g2.z * n2 + g3.z * n3;
        acc.w += g0.w * n0 + g1.w * n1 + g2.w * n2 + g3.w * n3;
    }
    for (; j < end; ++j) {
        int2 e0 = edges[j];
        float nrm = __int_as_float(e0.y);
        float4 g = h4[(size_t)e0.x * CH4 + tx];
        acc.x += g.x * nrm; acc.y += g.y * nrm;
        acc.z += g.z * nrm; acc.w += g.w * nrm;
    }
    if (RELU_OUT) {
        acc.x = fmaxf(acc.x, 0.f); acc.y = fmaxf(acc.y, 0.f);
        acc.z = fmaxf(acc.z, 0.f); acc.w = fmaxf(acc.w, 0.f);
    }
    ((float4*)out)[(size_t)node * CH4 + tx] = acc;
}

// ---------------------------------------------------------------------------
extern "C" void kernel_launch(void* const* d_in, const int* in_sizes, int n_in,
                              void* d_out, int out_size, void* d_ws, size_t ws_size,
                              hipStream_t stream) {
    const float* x  = (const float*)d_in[0];   // [N,128]
    const int*   ei = (const int*)d_in[1];     // [2,E]
    const float* ew = (const float*)d_in[2];   // [E]
    const float* W1 = (const float*)d_in[3];
    const float* b1 = (const float*)d_in[4];
    const float* W2 = (const float*)d_in[5];
    const float* b2 = (const float*)d_in[6];
    float* out = (float*)d_out;                // [N,128]

    const int N = in_sizes[0] / CH;
    const int E = in_sizes[2];
    const int* src = ei;
    const int* dst = ei + E;

    // workspace layout (all 16B-aligned)
    size_t Np = ((size_t)N + 255) & ~(size_t)255;
    float* ws        = (float*)d_ws;
    float* dinv      = ws;                          // N floats (deg -> dinv)
    float* h         = dinv + Np;                   // N*CH floats
    int*   counts    = (int*)(h + (size_t)N * CH);  // N ints
    int*   row_start = counts + Np;                 // N ints
    int*   cursor    = row_start + Np;              // N ints
    int*   partials  = cursor + Np;                 // 64 ints
    int2*  edges     = (int2*)(partials + 64);      // E int2

    const int nbN    = (N + TPB - 1) / TPB;
    const int nbE    = (E + TPB - 1) / TPB;
    const int nbAgg  = (int)(((size_t)N * 32 + TPB - 1) / TPB);
    const int nbScan = (N + SCANB - 1) / SCANB;     // 49 <= 64
    const dim3 gGemm((N + 63) / 64, 2);             // 782 x 2 blocks

    // ---- CSR build + normalization (shared by both layers) ----
    k_init      <<<nbN, TPB, 0, stream>>>(dinv, counts, N);
    k_edge_pass1<<<nbE, TPB, 0, stream>>>(dst, ew, dinv, counts, E, N);
    k_scan1     <<<nbScan, SCANB, 0, stream>>>(counts, row_start, partials, dinv, N);
    k_scan2     <<<1, 64, 0, stream>>>(partials, nbScan);
    k_scan3     <<<nbScan, SCANB, 0, stream>>>(row_start, partials, cursor, N);
    k_fill      <<<nbE, TPB, 0, stream>>>(src, dst, ew, dinv, cursor, edges, E, N);

    // ---- layer 1: h = x@W1; d_out = aggregate(h) + b1 (ReLU deferred) ----
    k_gemm<0>      <<<gGemm, TPB, 0, stream>>>(x, W1, h, N);
    k_aggregate<0> <<<nbAgg, TPB, 0, stream>>>(h, row_start, counts, edges,
                                               dinv, b1, out, N);

    // ---- layer 2: h = relu(d_out)@W2; d_out = relu(aggregate(h) + b2) ----
    k_gemm<1>      <<<gGemm, TPB, 0, stream>>>(out, W2, h, N);
    k_aggregate<1> <<<nbAgg, TPB, 0, stream>>>(h, row_start, counts, edges,
                                               dinv, b2, out, N);
}

// Round 6
// 303.321 us; speedup vs baseline: 7.5222x; 1.1073x over previous
//
#include <hip/hip_runtime.h>
#include <math.h>

// GCN 2-layer forward on MI355X — round 6:
//  * CSR build: rank-returning atomic pass (2E atomics, was 3E), atomic-free fill
//  * edge pass fused into gemm1 (block-specialized) -> atomics hide under MFMA
//  * norm (ew*dinv[src]) computed+written-back in aggregate<0>, reused by <1>
//  * aggregate: 8/4-wide unrolled gather groups for MLP
#define CH   128
#define CH4  32          // CH / 4 (float4 granularity)
#define TPB  256
#define SCANB 1024

typedef __attribute__((ext_vector_type(8))) short short8;   // 8 bf16 (4 VGPRs)
typedef __attribute__((ext_vector_type(4))) float floatx4;  // MFMA acc

// round-to-nearest-even fp32 -> bf16 (bit pattern in short)
static __device__ __forceinline__ short f2bf(float f) {
    unsigned u = __float_as_uint(f);
    unsigned r = (u + 0x7fffu + ((u >> 16) & 1u)) >> 16;
    return (short)r;
}
static __device__ __forceinline__ float bf2f(short s) {
    return __uint_as_float(((unsigned)(unsigned short)s) << 16);
}

// ---------------------------------------------------------------------------
// init: deg = 1 (self-loop), counts = 0
// ---------------------------------------------------------------------------
__global__ void k_init(float* __restrict__ deg, int* __restrict__ counts, int n) {
    int i = blockIdx.x * blockDim.x + threadIdx.x;
    if (i < n) { deg[i] = 1.0f; counts[i] = 0; }
}

// ---------------------------------------------------------------------------
// bf16-MFMA GEMM body (3-term Markidis split, fp32-accurate).
// Block = 4 waves; wave wv owns rows [tile*64+wv*16, +16) x 64 cols (colh).
// Frag layouts (m89/m91/m120-verified):
//   A: m = lane&15, k = (lane>>4)*8 + j ;  B mirrored ;  D: col=lane&15, row=(lane>>4)*4+reg
// ---------------------------------------------------------------------------
template<int RELU_IN>
static __device__ __forceinline__ void gemm_body(
        const float* __restrict__ X, const float* __restrict__ W,
        float* __restrict__ H, int n, int tile, int colh, int tid) {
    __shared__ __align__(16) short sW[2][4][4][64][8];   // 32 KB: hi/lo B-frags
    for (int i = tid; i < 128 * 64; i += TPB) {
        int k  = i >> 6;
        int nn = i & 63;
        float w = W[k * CH + colh * 64 + nn];             // coalesced over nn
        short hi = f2bf(w);
        short lo = f2bf(w - bf2f(hi));
        int kt = k >> 5, q = (k & 31) >> 3, j = k & 7;
        int ns = nn >> 4, ln = q * 16 + (nn & 15);
        sW[0][kt][ns][ln][j] = hi;
        sW[1][kt][ns][ln][j] = lo;
    }
    __syncthreads();

    const int lane = tid & 63;
    const int wv   = tid >> 6;          // wave 0..3
    const int q    = lane >> 4;         // quad 0..3
    const int m    = lane & 15;
    const int row0 = tile * 64 + wv * 16;
    if (row0 >= n) return;

    int rrow = row0 + m;
    if (rrow > n - 1) rrow = n - 1;     // clamp loads; stores guarded below

    const float4* xr = (const float4*)(X + (size_t)rrow * CH);
    float4 xa[4][2];
    #pragma unroll
    for (int kt = 0; kt < 4; ++kt) {
        xa[kt][0] = xr[kt * 8 + q * 2 + 0];
        xa[kt][1] = xr[kt * 8 + q * 2 + 1];
    }

    floatx4 acc[4];
    #pragma unroll
    for (int ns = 0; ns < 4; ++ns) acc[ns] = (floatx4){0.f, 0.f, 0.f, 0.f};

    #pragma unroll
    for (int kt = 0; kt < 4; ++kt) {
        float xf[8] = { xa[kt][0].x, xa[kt][0].y, xa[kt][0].z, xa[kt][0].w,
                        xa[kt][1].x, xa[kt][1].y, xa[kt][1].z, xa[kt][1].w };
        short8 ah, al;
        #pragma unroll
        for (int j = 0; j < 8; ++j) {
            float v = xf[j];
            if (RELU_IN) v = fmaxf(v, 0.f);
            short h = f2bf(v);
            ah[j] = h;
            al[j] = f2bf(v - bf2f(h));
        }
        #pragma unroll
        for (int ns = 0; ns < 4; ++ns) {
            short8 bh = *(const short8*)&sW[0][kt][ns][lane][0];
            short8 bl = *(const short8*)&sW[1][kt][ns][lane][0];
            acc[ns] = __builtin_amdgcn_mfma_f32_16x16x32_bf16(ah, bh, acc[ns], 0, 0, 0);
            acc[ns] = __builtin_amdgcn_mfma_f32_16x16x32_bf16(al, bh, acc[ns], 0, 0, 0);
            acc[ns] = __builtin_amdgcn_mfma_f32_16x16x32_bf16(ah, bl, acc[ns], 0, 0, 0);
        }
    }

    #pragma unroll
    for (int ns = 0; ns < 4; ++ns) {
        #pragma unroll
        for (int reg = 0; reg < 4; ++reg) {
            int r = row0 + q * 4 + reg;
            if (r < n)
                H[(size_t)r * CH + colh * 64 + ns * 16 + m] = acc[ns][reg];
        }
    }
}

template<int RELU_IN>
__global__ __launch_bounds__(TPB, 4)
void k_gemm(const float* __restrict__ X, const float* __restrict__ W,
            float* __restrict__ H, int n) {
    gemm_body<RELU_IN>(X, W, H, n, (int)blockIdx.x >> 1, (int)blockIdx.x & 1,
                       threadIdx.x);
}

// fused: blocks [0, ngemm2) do gemm1; the rest do the per-edge atomic pass
// (deg accumulate + rank = in-bucket position). Atomics hide under MFMA.
__global__ __launch_bounds__(TPB, 4)
void k_gemm_rank(const float* __restrict__ X, const float* __restrict__ W,
                 float* __restrict__ H, int n,
                 const int* __restrict__ dst, const float* __restrict__ ew,
                 float* __restrict__ deg, int* __restrict__ counts,
                 int* __restrict__ rank, int E, int ngemm2) {
    int bx = blockIdx.x;
    if (bx < ngemm2) {
        gemm_body<0>(X, W, H, n, bx >> 1, bx & 1, threadIdx.x);
    } else {
        int e = (bx - ngemm2) * TPB + threadIdx.x;
        if (e < E) {
            int d = dst[e];
            if ((unsigned)d < (unsigned)n) {
                unsafeAtomicAdd(&deg[d], ew[e]);
                rank[e] = atomicAdd(&counts[d], 1);
            }
        }
    }
}

// ---------------------------------------------------------------------------
// scan pass 1 (+ fused deg -> dinv conversion)
// ---------------------------------------------------------------------------
__global__ __launch_bounds__(SCANB)
void k_scan1(const int* __restrict__ counts, int* __restrict__ row_start,
             int* __restrict__ partials, float* __restrict__ deg, int n) {
    __shared__ int s[SCANB];
    int gid = blockIdx.x * SCANB + threadIdx.x;
    int v = (gid < n) ? counts[gid] : 0;
    s[threadIdx.x] = v;
    __syncthreads();
    for (int off = 1; off < SCANB; off <<= 1) {
        int t = (threadIdx.x >= off) ? s[threadIdx.x - off] : 0;
        __syncthreads();
        s[threadIdx.x] += t;
        __syncthreads();
    }
    if (gid < n) {
        row_start[gid] = s[threadIdx.x] - v;   // exclusive within block
        float d = deg[gid];
        deg[gid] = (d > 0.0f) ? rsqrtf(d) : 0.0f;   // deg -> dinv in place
    }
    if (threadIdx.x == SCANB - 1) partials[blockIdx.x] = s[SCANB - 1];
}

__global__ __launch_bounds__(64)
void k_scan2(int* __restrict__ partials, int nb) {     // nb <= 64
    __shared__ int s[64];
    int v = (threadIdx.x < nb) ? partials[threadIdx.x] : 0;
    s[threadIdx.x] = v;
    __syncthreads();
    for (int off = 1; off < 64; off <<= 1) {
        int t = (threadIdx.x >= off) ? s[threadIdx.x - off] : 0;
        __syncthreads();
        s[threadIdx.x] += t;
        __syncthreads();
    }
    if (threadIdx.x < nb) partials[threadIdx.x] = s[threadIdx.x] - v;  // exclusive
}

__global__ __launch_bounds__(SCANB)
void k_scan3(int* __restrict__ row_start, const int* __restrict__ partials, int n) {
    int gid = blockIdx.x * SCANB + threadIdx.x;
    if (gid < n) row_start[gid] += partials[blockIdx.x];
}

// atomic-free fill: edges[row_start[dst] + rank[e]] = {src, raw ew}
__global__ void k_fill(const int* __restrict__ src, const int* __restrict__ dst,
                       const float* __restrict__ ew, const int* __restrict__ row_start,
                       const int* __restrict__ rank, int2* __restrict__ edges,
                       int E, int n) {
    int e = blockIdx.x * blockDim.x + threadIdx.x;
    if (e >= E) return;
    int s = src[e], d = dst[e];
    if ((unsigned)s >= (unsigned)n || (unsigned)d >= (unsigned)n) return;
    edges[row_start[d] + rank[e]] = make_int2(s, __float_as_int(ew[e]));
}

// ---------------------------------------------------------------------------
// CSR aggregate: out[i] = (relu?)( h[i]*di^2 + bias + di * sum_j w'_j * h[s_j] )
// where w' = ew * dinv[src].  FIXUP=1: compute w' from raw ew and write it
// back into edges (each edge owned by exactly one node -> race-free); the
// second aggregate reuses the stored w'.
// 32 lanes per node (4 ch each); 8-then-4-wide unrolled gather groups.
// ---------------------------------------------------------------------------
template<int RELU_OUT, int FIXUP>
__global__ __launch_bounds__(TPB)
void k_aggregate(const float* __restrict__ h, const int* __restrict__ row_start,
                 const int* __restrict__ counts, int2* __restrict__ edges,
                 const float* __restrict__ dinv, const float* __restrict__ bias,
                 float* __restrict__ out, int n) {
    int t = blockIdx.x * blockDim.x + threadIdx.x;
    int node = t >> 5;
    if (node >= n) return;
    int tx = t & 31;

    const float4* h4 = (const float4*)h;
    float di = dinv[node];
    float4 b  = ((const float4*)bias)[tx];
    float4 hv = h4[(size_t)node * CH4 + tx];
    float4 acc = make_float4(0.f, 0.f, 0.f, 0.f);   // edge sum (x di at end)

    int j   = row_start[node];
    int end = j + counts[node];

    for (; j + 8 <= end; j += 8) {
        int2 e[8];
        #pragma unroll
        for (int i = 0; i < 8; ++i) e[i] = edges[j + i];
        float w[8];
        #pragma unroll
        for (int i = 0; i < 8; ++i) {
            w[i] = __int_as_float(e[i].y);
            if (FIXUP) w[i] *= dinv[e[i].x];
        }
        if (FIXUP && tx == 0) {
            #pragma unroll
            for (int i = 0; i < 8; ++i) edges[j + i].y = __float_as_int(w[i]);
        }
        #pragma unroll
        for (int i = 0; i < 8; ++i) {
            float4 g = h4[(size_t)e[i].x * CH4 + tx];
            acc.x += g.x * w[i]; acc.y += g.y * w[i];
            acc.z += g.z * w[i]; acc.w += g.w * w[i];
        }
    }
    if (j + 4 <= end) {
        int2 e[4];
        #pragma unroll
        for (int i = 0; i < 4; ++i) e[i] = edges[j + i];
        float w[4];
        #pragma unroll
        for (int i = 0; i < 4; ++i) {
            w[i] = __int_as_float(e[i].y);
            if (FIXUP) w[i] *= dinv[e[i].x];
        }
        if (FIXUP && tx == 0) {
            #pragma unroll
            for (int i = 0; i < 4; ++i) edges[j + i].y = __float_as_int(w[i]);
        }
        #pragma unroll
        for (int i = 0; i < 4; ++i) {
            float4 g = h4[(size_t)e[i].x * CH4 + tx];
            acc.x += g.x * w[i]; acc.y += g.y * w[i];
            acc.z += g.z * w[i]; acc.w += g.w * w[i];
        }
        j += 4;
    }
    for (; j < end; ++j) {
        int2 e0 = edges[j];
        float w0 = __int_as_float(e0.y);
        if (FIXUP) w0 *= dinv[e0.x];
        if (FIXUP && tx == 0) edges[j].y = __float_as_int(w0);
        float4 g = h4[(size_t)e0.x * CH4 + tx];
        acc.x += g.x * w0; acc.y += g.y * w0;
        acc.z += g.z * w0; acc.w += g.w * w0;
    }

    float sc = di * di;
    float4 o = make_float4(hv.x * sc + b.x + di * acc.x,
                           hv.y * sc + b.y + di * acc.y,
                           hv.z * sc + b.z + di * acc.z,
                           hv.w * sc + b.w + di * acc.w);
    if (RELU_OUT) {
        o.x = fmaxf(o.x, 0.f); o.y = fmaxf(o.y, 0.f);
        o.z = fmaxf(o.z, 0.f); o.w = fmaxf(o.w, 0.f);
    }
    ((float4*)out)[(size_t)node * CH4 + tx] = o;
}

// ---------------------------------------------------------------------------
extern "C" void kernel_launch(void* const* d_in, const int* in_sizes, int n_in,
                              void* d_out, int out_size, void* d_ws, size_t ws_size,
                              hipStream_t stream) {
    const float* x  = (const float*)d_in[0];   // [N,128]
    const int*   ei = (const int*)d_in[1];     // [2,E]
    const float* ew = (const float*)d_in[2];   // [E]
    const float* W1 = (const float*)d_in[3];
    const float* b1 = (const float*)d_in[4];
    const float* W2 = (const float*)d_in[5];
    const float* b2 = (const float*)d_in[6];
    float* out = (float*)d_out;                // [N,128]

    const int N = in_sizes[0] / CH;
    const int E = in_sizes[2];
    const int* src = ei;
    const int* dst = ei + E;

    // workspace layout (16B-aligned)
    size_t Np = ((size_t)N + 255) & ~(size_t)255;
    float* ws        = (float*)d_ws;
    float* dinv      = ws;                          // N floats (deg -> dinv)
    float* h         = dinv + Np;                   // N*CH floats
    int*   counts    = (int*)(h + (size_t)N * CH);  // N ints
    int*   row_start = counts + Np;                 // N ints
    int*   rank      = row_start + Np;              // E ints
    int*   partials  = rank + (((size_t)E + 63) & ~(size_t)63); // 64 ints
    int2*  edges     = (int2*)(partials + 64);      // E int2

    const int nbN    = (N + TPB - 1) / TPB;
    const int nbE    = (E + TPB - 1) / TPB;
    const int nbAgg  = (int)(((size_t)N * 32 + TPB - 1) / TPB);
    const int nbScan = (N + SCANB - 1) / SCANB;     // 49 <= 64
    const int nbGemm2 = 2 * ((N + 63) / 64);        // 1564 blocks

    // ---- init + fused(gemm1 | edge atomic pass) ----
    k_init     <<<nbN, TPB, 0, stream>>>(dinv, counts, N);
    k_gemm_rank<<<nbGemm2 + nbE, TPB, 0, stream>>>(x, W1, h, N, dst, ew,
                                                   dinv, counts, rank, E, nbGemm2);
    // ---- CSR finalize ----
    k_scan1    <<<nbScan, SCANB, 0, stream>>>(counts, row_start, partials, dinv, N);
    k_scan2    <<<1, 64, 0, stream>>>(partials, nbScan);
    k_scan3    <<<nbScan, SCANB, 0, stream>>>(row_start, partials, N);
    k_fill     <<<nbE, TPB, 0, stream>>>(src, dst, ew, row_start, rank, edges, E, N);

    // ---- layer 1 aggregate (computes+stores w' = ew*dinv[src]) ----
    k_aggregate<0,1><<<nbAgg, TPB, 0, stream>>>(h, row_start, counts, edges,
                                                dinv, b1, out, N);
    // ---- layer 2 ----
    k_gemm<1>       <<<nbGemm2, TPB, 0, stream>>>(out, W2, h, N);
    k_aggregate<1,0><<<nbAgg, TPB, 0, stream>>>(h, row_start, counts, edges,
                                                dinv, b2, out, N);
}

// Round 7
// 260.261 us; speedup vs baseline: 8.7668x; 1.1654x over previous
//
#include <hip/hip_runtime.h>
#include <math.h>

// GCN 2-layer forward on MI355X — round 7:
//  * atomic pass: 1 atomic/edge (rank only); deg derived from CSR buckets
//  * fused kernel: edge blocks FIRST, gemm1 blocks behind them
//  * W pre-split once into bf16 hi/lo MFMA-fragment images (k_prep) ->
//    gemm staging = contiguous float4 copy (no LDS bank conflicts, no VALU)
#define CH   128
#define CH4  32          // CH / 4 (float4 granularity)
#define TPB  256
#define SCANB 1024
#define WIMG 16384       // shorts per (layer,colh) fragment image (32 KB)

typedef __attribute__((ext_vector_type(8))) short short8;   // 8 bf16 (4 VGPRs)
typedef __attribute__((ext_vector_type(4))) float floatx4;  // MFMA acc

// round-to-nearest-even fp32 -> bf16 (bit pattern in short)
static __device__ __forceinline__ short f2bf(float f) {
    unsigned u = __float_as_uint(f);
    unsigned r = (u + 0x7fffu + ((u >> 16) & 1u)) >> 16;
    return (short)r;
}
static __device__ __forceinline__ float bf2f(short s) {
    return __uint_as_float(((unsigned)(unsigned short)s) << 16);
}

// ---------------------------------------------------------------------------
// k_prep: split W1,W2 into bf16 hi/lo B-fragment images.
// Image per (layer,colh): short [2][4][4][64][8]  (h, kt, ns, ln, j) = 32 KB.
//   k = kt*32 + (ln>>4)*8 + j ;  col = colh*64 + ns*16 + (ln&15)
// ---------------------------------------------------------------------------
__global__ void k_prep(const float* __restrict__ W1, const float* __restrict__ W2,
                       short* __restrict__ Wsplit) {
    int i = blockIdx.x * blockDim.x + threadIdx.x;   // over 2*128*128
    if (i >= 2 * CH * CH) return;
    int layer = i >> 14;
    int idx   = i & 16383;
    int k = idx >> 7, c = idx & 127;
    float w = (layer ? W2 : W1)[k * CH + c];
    short hi = f2bf(w);
    short lo = f2bf(w - bf2f(hi));
    int colh = c >> 6, nn = c & 63;
    int kt = k >> 5, q = (k & 31) >> 3, j = k & 7;
    int ns = nn >> 4, ln = q * 16 + (nn & 15);
    size_t base = (size_t)(layer * 2 + colh) * WIMG;
    size_t off  = ((size_t)(kt * 4 + ns) * 64 + ln) * 8 + j;   // h=0
    Wsplit[base + off]        = hi;
    Wsplit[base + 8192 + off] = lo;                            // h=1 stride
}

// ---------------------------------------------------------------------------
// bf16-MFMA GEMM body (3-term Markidis split, fp32-accurate).
// Wfrag = pre-split image for this colh (32 KB, contiguous copy to LDS).
// Frag layouts (m89/m91/m120-verified):
//   A: m=lane&15, k=(lane>>4)*8+j ; B mirrored ; D: col=lane&15, row=(lane>>4)*4+reg
// ---------------------------------------------------------------------------
template<int RELU_IN>
static __device__ __forceinline__ void gemm_body(
        const float* __restrict__ X, const short* __restrict__ Wfrag,
        float* __restrict__ H, int n, int tile, int colh, int tid) {
    __shared__ __align__(16) short sW[2][4][4][64][8];   // 32 KB
    {
        const float4* gsrc = (const float4*)Wfrag;       // 2048 float4
        float4* ldst = (float4*)sW;
        #pragma unroll
        for (int i = 0; i < 8; ++i)
            ldst[i * TPB + tid] = gsrc[i * TPB + tid];
    }
    __syncthreads();

    const int lane = tid & 63;
    const int wv   = tid >> 6;          // wave 0..3
    const int q    = lane >> 4;         // quad 0..3
    const int m    = lane & 15;
    const int row0 = tile * 64 + wv * 16;
    if (row0 >= n) return;

    int rrow = row0 + m;
    if (rrow > n - 1) rrow = n - 1;     // clamp loads; stores guarded below

    const float4* xr = (const float4*)(X + (size_t)rrow * CH);
    float4 xa[4][2];
    #pragma unroll
    for (int kt = 0; kt < 4; ++kt) {
        xa[kt][0] = xr[kt * 8 + q * 2 + 0];
        xa[kt][1] = xr[kt * 8 + q * 2 + 1];
    }

    floatx4 acc[4];
    #pragma unroll
    for (int ns = 0; ns < 4; ++ns) acc[ns] = (floatx4){0.f, 0.f, 0.f, 0.f};

    #pragma unroll
    for (int kt = 0; kt < 4; ++kt) {
        float xf[8] = { xa[kt][0].x, xa[kt][0].y, xa[kt][0].z, xa[kt][0].w,
                        xa[kt][1].x, xa[kt][1].y, xa[kt][1].z, xa[kt][1].w };
        short8 ah, al;
        #pragma unroll
        for (int j = 0; j < 8; ++j) {
            float v = xf[j];
            if (RELU_IN) v = fmaxf(v, 0.f);
            short h = f2bf(v);
            ah[j] = h;
            al[j] = f2bf(v - bf2f(h));
        }
        #pragma unroll
        for (int ns = 0; ns < 4; ++ns) {
            short8 bh = *(const short8*)&sW[0][kt][ns][lane][0];
            short8 bl = *(const short8*)&sW[1][kt][ns][lane][0];
            acc[ns] = __builtin_amdgcn_mfma_f32_16x16x32_bf16(ah, bh, acc[ns], 0, 0, 0);
            acc[ns] = __builtin_amdgcn_mfma_f32_16x16x32_bf16(al, bh, acc[ns], 0, 0, 0);
            acc[ns] = __builtin_amdgcn_mfma_f32_16x16x32_bf16(ah, bl, acc[ns], 0, 0, 0);
        }
    }

    #pragma unroll
    for (int ns = 0; ns < 4; ++ns) {
        #pragma unroll
        for (int reg = 0; reg < 4; ++reg) {
            int r = row0 + q * 4 + reg;
            if (r < n)
                H[(size_t)r * CH + colh * 64 + ns * 16 + m] = acc[ns][reg];
        }
    }
}

template<int RELU_IN>
__global__ __launch_bounds__(TPB, 4)
void k_gemm(const float* __restrict__ X, const short* __restrict__ Wsplit,
            float* __restrict__ H, int n) {
    int colh = (int)blockIdx.x & 1;
    gemm_body<RELU_IN>(X, Wsplit + (size_t)colh * WIMG, H, n,
                       (int)blockIdx.x >> 1, colh, threadIdx.x);
}

// fused: blocks [0, nbE) do the per-edge rank atomic (long pole, dispatched
// first); blocks [nbE, nbE+ngemm2) do gemm1.
__global__ __launch_bounds__(TPB, 4)
void k_gemm_rank(const float* __restrict__ X, const short* __restrict__ Wsplit,
                 float* __restrict__ H, int n,
                 const int* __restrict__ dst, int* __restrict__ counts,
                 int* __restrict__ rank, int E, int nbE) {
    int bx = blockIdx.x;
    if (bx < nbE) {
        int e = bx * TPB + threadIdx.x;
        if (e < E) {
            int d = dst[e];
            if ((unsigned)d < (unsigned)n)
                rank[e] = atomicAdd(&counts[d], 1);
        }
    } else {
        bx -= nbE;
        int colh = bx & 1;
        gemm_body<0>(X, Wsplit + (size_t)colh * WIMG, H, n, bx >> 1, colh,
                     threadIdx.x);
    }
}

// ---------------------------------------------------------------------------
// 3-pass exclusive prefix sum over counts[n] -> row_start[n]
// ---------------------------------------------------------------------------
__global__ __launch_bounds__(SCANB)
void k_scan1(const int* __restrict__ counts, int* __restrict__ row_start,
             int* __restrict__ partials, int n) {
    __shared__ int s[SCANB];
    int gid = blockIdx.x * SCANB + threadIdx.x;
    int v = (gid < n) ? counts[gid] : 0;
    s[threadIdx.x] = v;
    __syncthreads();
    for (int off = 1; off < SCANB; off <<= 1) {
        int t = (threadIdx.x >= off) ? s[threadIdx.x - off] : 0;
        __syncthreads();
        s[threadIdx.x] += t;
        __syncthreads();
    }
    if (gid < n) row_start[gid] = s[threadIdx.x] - v;
    if (threadIdx.x == SCANB - 1) partials[blockIdx.x] = s[SCANB - 1];
}

__global__ __launch_bounds__(64)
void k_scan2(int* __restrict__ partials, int nb) {     // nb <= 64
    __shared__ int s[64];
    int v = (threadIdx.x < nb) ? partials[threadIdx.x] : 0;
    s[threadIdx.x] = v;
    __syncthreads();
    for (int off = 1; off < 64; off <<= 1) {
        int t = (threadIdx.x >= off) ? s[threadIdx.x - off] : 0;
        __syncthreads();
        s[threadIdx.x] += t;
        __syncthreads();
    }
    if (threadIdx.x < nb) partials[threadIdx.x] = s[threadIdx.x] - v;
}

__global__ __launch_bounds__(SCANB)
void k_scan3(int* __restrict__ row_start, const int* __restrict__ partials, int n) {
    int gid = blockIdx.x * SCANB + threadIdx.x;
    if (gid < n) row_start[gid] += partials[blockIdx.x];
}

// atomic-free fill: edges[row_start[dst] + rank[e]] = {src, raw ew}
__global__ void k_fill(const int* __restrict__ src, const int* __restrict__ dst,
                       const float* __restrict__ ew, const int* __restrict__ row_start,
                       const int* __restrict__ rank, int2* __restrict__ edges,
                       int E, int n) {
    int e = blockIdx.x * blockDim.x + threadIdx.x;
    if (e >= E) return;
    int s = src[e], d = dst[e];
    if ((unsigned)s >= (unsigned)n || (unsigned)d >= (unsigned)n) return;
    edges[row_start[d] + rank[e]] = make_int2(s, __float_as_int(ew[e]));
}

// per-node: deg = 1 + sum(raw ew over bucket); dinv = rsqrt(deg)
__global__ void k_deg(const int* __restrict__ row_start, const int* __restrict__ counts,
                      const int2* __restrict__ edges, float* __restrict__ dinv, int n) {
    int i = blockIdx.x * blockDim.x + threadIdx.x;
    if (i >= n) return;
    int j = row_start[i], end = j + counts[i];
    float sum = 1.0f;                      // self-loop
    for (; j < end; ++j) sum += __int_as_float(edges[j].y);
    dinv[i] = rsqrtf(sum);                 // deg >= 1 always
}

// ---------------------------------------------------------------------------
// CSR aggregate: out[i] = (relu?)( h[i]*di^2 + bias + di * sum_j w'_j * h[s_j] )
// FIXUP=1: w' = raw_ew * dinv[src], written back (edge owned by one node).
// ---------------------------------------------------------------------------
template<int RELU_OUT, int FIXUP>
__global__ __launch_bounds__(TPB)
void k_aggregate(const float* __restrict__ h, const int* __restrict__ row_start,
                 const int* __restrict__ counts, int2* __restrict__ edges,
                 const float* __restrict__ dinv, const float* __restrict__ bias,
                 float* __restrict__ out, int n) {
    int t = blockIdx.x * blockDim.x + threadIdx.x;
    int node = t >> 5;
    if (node >= n) return;
    int tx = t & 31;

    const float4* h4 = (const float4*)h;
    float di = dinv[node];
    float4 b  = ((const float4*)bias)[tx];
    float4 hv = h4[(size_t)node * CH4 + tx];
    float4 acc = make_float4(0.f, 0.f, 0.f, 0.f);

    int j   = row_start[node];
    int end = j + counts[node];

    for (; j + 8 <= end; j += 8) {
        int2 e[8];
        #pragma unroll
        for (int i = 0; i < 8; ++i) e[i] = edges[j + i];
        float w[8];
        #pragma unroll
        for (int i = 0; i < 8; ++i) {
            w[i] = __int_as_float(e[i].y);
            if (FIXUP) w[i] *= dinv[e[i].x];
        }
        if (FIXUP && tx == 0) {
            #pragma unroll
            for (int i = 0; i < 8; ++i) edges[j + i].y = __float_as_int(w[i]);
        }
        #pragma unroll
        for (int i = 0; i < 8; ++i) {
            float4 g = h4[(size_t)e[i].x * CH4 + tx];
            acc.x += g.x * w[i]; acc.y += g.y * w[i];
            acc.z += g.z * w[i]; acc.w += g.w * w[i];
        }
    }
    if (j + 4 <= end) {
        int2 e[4];
        #pragma unroll
        for (int i = 0; i < 4; ++i) e[i] = edges[j + i];
        float w[4];
        #pragma unroll
        for (int i = 0; i < 4; ++i) {
            w[i] = __int_as_float(e[i].y);
            if (FIXUP) w[i] *= dinv[e[i].x];
        }
        if (FIXUP && tx == 0) {
            #pragma unroll
            for (int i = 0; i < 4; ++i) edges[j + i].y = __float_as_int(w[i]);
        }
        #pragma unroll
        for (int i = 0; i < 4; ++i) {
            float4 g = h4[(size_t)e[i].x * CH4 + tx];
            acc.x += g.x * w[i]; acc.y += g.y * w[i];
            acc.z += g.z * w[i]; acc.w += g.w * w[i];
        }
        j += 4;
    }
    for (; j < end; ++j) {
        int2 e0 = edges[j];
        float w0 = __int_as_float(e0.y);
        if (FIXUP) w0 *= dinv[e0.x];
        if (FIXUP && tx == 0) edges[j].y = __float_as_int(w0);
        float4 g = h4[(size_t)e0.x * CH4 + tx];
        acc.x += g.x * w0; acc.y += g.y * w0;
        acc.z += g.z * w0; acc.w += g.w * w0;
    }

    float sc = di * di;
    float4 o = make_float4(hv.x * sc + b.x + di * acc.x,
                           hv.y * sc + b.y + di * acc.y,
                           hv.z * sc + b.z + di * acc.z,
                           hv.w * sc + b.w + di * acc.w);
    if (RELU_OUT) {
        o.x = fmaxf(o.x, 0.f); o.y = fmaxf(o.y, 0.f);
        o.z = fmaxf(o.z, 0.f); o.w = fmaxf(o.w, 0.f);
    }
    ((float4*)out)[(size_t)node * CH4 + tx] = o;
}

// ---------------------------------------------------------------------------
extern "C" void kernel_launch(void* const* d_in, const int* in_sizes, int n_in,
                              void* d_out, int out_size, void* d_ws, size_t ws_size,
                              hipStream_t stream) {
    const float* x  = (const float*)d_in[0];   // [N,128]
    const int*   ei = (const int*)d_in[1];     // [2,E]
    const float* ew = (const float*)d_in[2];   // [E]
    const float* W1 = (const float*)d_in[3];
    const float* b1 = (const float*)d_in[4];
    const float* W2 = (const float*)d_in[5];
    const float* b2 = (const float*)d_in[6];
    float* out = (float*)d_out;                // [N,128]

    const int N = in_sizes[0] / CH;
    const int E = in_sizes[2];
    const int* src = ei;
    const int* dst = ei + E;

    // workspace layout (16B-aligned)
    size_t Np = ((size_t)N + 255) & ~(size_t)255;
    float* ws        = (float*)d_ws;
    float* dinv      = ws;                          // N floats
    float* h         = dinv + Np;                   // N*CH floats
    int*   counts    = (int*)(h + (size_t)N * CH);  // N ints
    int*   row_start = counts + Np;                 // N ints
    int*   rank      = row_start + Np;              // E ints
    int*   partials  = rank + (((size_t)E + 63) & ~(size_t)63); // 64 ints
    int2*  edges     = (int2*)(partials + 64);      // E int2
    short* Wsplit    = (short*)(edges + E);         // 4*WIMG shorts (128 KB)

    const int nbN    = (N + TPB - 1) / TPB;
    const int nbE    = (E + TPB - 1) / TPB;
    const int nbAgg  = (int)(((size_t)N * 32 + TPB - 1) / TPB);
    const int nbScan = (N + SCANB - 1) / SCANB;     // 49 <= 64
    const int nbGemm2 = 2 * ((N + 63) / 64);        // 1564 blocks
    const int nbPrep  = (2 * CH * CH + TPB - 1) / TPB;

    // ---- prep: counts = 0, W fragment images ----
    hipMemsetAsync(counts, 0, (size_t)N * sizeof(int), stream);
    k_prep     <<<nbPrep, TPB, 0, stream>>>(W1, W2, Wsplit);

    // ---- fused: edge rank pass (first) | gemm1 ----
    k_gemm_rank<<<nbE + nbGemm2, TPB, 0, stream>>>(x, Wsplit, h, N, dst,
                                                   counts, rank, E, nbE);
    // ---- CSR finalize ----
    k_scan1    <<<nbScan, SCANB, 0, stream>>>(counts, row_start, partials, N);
    k_scan2    <<<1, 64, 0, stream>>>(partials, nbScan);
    k_scan3    <<<nbScan, SCANB, 0, stream>>>(row_start, partials, N);
    k_fill     <<<nbE, TPB, 0, stream>>>(src, dst, ew, row_start, rank, edges, E, N);
    k_deg      <<<nbN, TPB, 0, stream>>>(row_start, counts, edges, dinv, N);

    // ---- layer 1 aggregate (computes+stores w' = ew*dinv[src]) ----
    k_aggregate<0,1><<<nbAgg, TPB, 0, stream>>>(h, row_start, counts, edges,
                                                dinv, b1, out, N);
    // ---- layer 2 ----
    k_gemm<1>       <<<nbGemm2, TPB, 0, stream>>>(out, Wsplit + 2 * WIMG, h, N);
    k_aggregate<1,0><<<nbAgg, TPB, 0, stream>>>(h, row_start, counts, edges,
                                                dinv, b2, out, N);
}

// Round 8
// 230.646 us; speedup vs baseline: 9.8925x; 1.1284x over previous
//
#include <hip/hip_runtime.h>
#include <math.h>

// GCN 2-layer forward on MI355X — round 8: h stored in bf16 (halves the
// aggregate's gather traffic, the current bottleneck at 146 MB/dispatch).
#define CH   128
#define CH4  32
#define TPB  256
#define SCANB 1024
#define WIMG 16384       // shorts per (layer,colh) fragment image (32 KB)

typedef __attribute__((ext_vector_type(8))) short short8;   // 8 bf16 (4 VGPRs)
typedef __attribute__((ext_vector_type(4))) float floatx4;  // MFMA acc

// round-to-nearest-even fp32 -> bf16 (bit pattern)
static __device__ __forceinline__ unsigned short f2bf(float f) {
    unsigned u = __float_as_uint(f);
    return (unsigned short)((u + 0x7fffu + ((u >> 16) & 1u)) >> 16);
}
static __device__ __forceinline__ float bf2f(unsigned short s) {
    return __uint_as_float(((unsigned)s) << 16);
}
static __device__ __forceinline__ float4 bf4_to_f4(ushort4 u) {
    return make_float4(bf2f(u.x), bf2f(u.y), bf2f(u.z), bf2f(u.w));
}

// ---------------------------------------------------------------------------
// k_prep: split W1,W2 into bf16 hi/lo B-fragment images (32 KB per colh).
// ---------------------------------------------------------------------------
__global__ void k_prep(const float* __restrict__ W1, const float* __restrict__ W2,
                       short* __restrict__ Wsplit) {
    int i = blockIdx.x * blockDim.x + threadIdx.x;   // over 2*128*128
    if (i >= 2 * CH * CH) return;
    int layer = i >> 14;
    int idx   = i & 16383;
    int k = idx >> 7, c = idx & 127;
    float w = (layer ? W2 : W1)[k * CH + c];
    unsigned short hi = f2bf(w);
    unsigned short lo = f2bf(w - bf2f(hi));
    int colh = c >> 6, nn = c & 63;
    int kt = k >> 5, q = (k & 31) >> 3, j = k & 7;
    int ns = nn >> 4, ln = q * 16 + (nn & 15);
    size_t base = (size_t)(layer * 2 + colh) * WIMG;
    size_t off  = ((size_t)(kt * 4 + ns) * 64 + ln) * 8 + j;
    Wsplit[base + off]        = (short)hi;
    Wsplit[base + 8192 + off] = (short)lo;
}

// ---------------------------------------------------------------------------
// bf16-MFMA GEMM body (3-term Markidis split, fp32-accurate accumulation),
// output stored as bf16. Frag layouts (m89/m91/m120-verified):
//   A: m=lane&15, k=(lane>>4)*8+j ; B mirrored ; D: col=lane&15, row=(lane>>4)*4+reg
// ---------------------------------------------------------------------------
template<int RELU_IN>
static __device__ __forceinline__ void gemm_body(
        const float* __restrict__ X, const short* __restrict__ Wfrag,
        unsigned short* __restrict__ H, int n, int tile, int colh, int tid) {
    __shared__ __align__(16) short sW[2][4][4][64][8];   // 32 KB
    {
        const float4* gsrc = (const float4*)Wfrag;       // 2048 float4
        float4* ldst = (float4*)sW;
        #pragma unroll
        for (int i = 0; i < 8; ++i)
            ldst[i * TPB + tid] = gsrc[i * TPB + tid];
    }
    __syncthreads();

    const int lane = tid & 63;
    const int wv   = tid >> 6;
    const int q    = lane >> 4;
    const int m    = lane & 15;
    const int row0 = tile * 64 + wv * 16;
    if (row0 >= n) return;

    int rrow = row0 + m;
    if (rrow > n - 1) rrow = n - 1;     // clamp loads; stores guarded below

    const float4* xr = (const float4*)(X + (size_t)rrow * CH);
    float4 xa[4][2];
    #pragma unroll
    for (int kt = 0; kt < 4; ++kt) {
        xa[kt][0] = xr[kt * 8 + q * 2 + 0];
        xa[kt][1] = xr[kt * 8 + q * 2 + 1];
    }

    floatx4 acc[4];
    #pragma unroll
    for (int ns = 0; ns < 4; ++ns) acc[ns] = (floatx4){0.f, 0.f, 0.f, 0.f};

    #pragma unroll
    for (int kt = 0; kt < 4; ++kt) {
        float xf[8] = { xa[kt][0].x, xa[kt][0].y, xa[kt][0].z, xa[kt][0].w,
                        xa[kt][1].x, xa[kt][1].y, xa[kt][1].z, xa[kt][1].w };
        short8 ah, al;
        #pragma unroll
        for (int j = 0; j < 8; ++j) {
            float v = xf[j];
            if (RELU_IN) v = fmaxf(v, 0.f);
            unsigned short h = f2bf(v);
            ah[j] = (short)h;
            al[j] = (short)f2bf(v - bf2f(h));
        }
        #pragma unroll
        for (int ns = 0; ns < 4; ++ns) {
            short8 bh = *(const short8*)&sW[0][kt][ns][lane][0];
            short8 bl = *(const short8*)&sW[1][kt][ns][lane][0];
            acc[ns] = __builtin_amdgcn_mfma_f32_16x16x32_bf16(ah, bh, acc[ns], 0, 0, 0);
            acc[ns] = __builtin_amdgcn_mfma_f32_16x16x32_bf16(al, bh, acc[ns], 0, 0, 0);
            acc[ns] = __builtin_amdgcn_mfma_f32_16x16x32_bf16(ah, bl, acc[ns], 0, 0, 0);
        }
    }

    #pragma unroll
    for (int ns = 0; ns < 4; ++ns) {
        #pragma unroll
        for (int reg = 0; reg < 4; ++reg) {
            int r = row0 + q * 4 + reg;
            if (r < n)
                H[(size_t)r * CH + colh * 64 + ns * 16 + m] = f2bf(acc[ns][reg]);
        }
    }
}

template<int RELU_IN>
__global__ __launch_bounds__(TPB, 4)
void k_gemm(const float* __restrict__ X, const short* __restrict__ Wsplit,
            unsigned short* __restrict__ H, int n) {
    int colh = (int)blockIdx.x & 1;
    gemm_body<RELU_IN>(X, Wsplit + (size_t)colh * WIMG, H, n,
                       (int)blockIdx.x >> 1, colh, threadIdx.x);
}

// fused: blocks [0, nbE) do the per-edge rank atomic (long pole, first);
// blocks [nbE, nbE+ngemm2) do gemm1.
__global__ __launch_bounds__(TPB, 4)
void k_gemm_rank(const float* __restrict__ X, const short* __restrict__ Wsplit,
                 unsigned short* __restrict__ H, int n,
                 const int* __restrict__ dst, int* __restrict__ counts,
                 int* __restrict__ rank, int E, int nbE) {
    int bx = blockIdx.x;
    if (bx < nbE) {
        int e = bx * TPB + threadIdx.x;
        if (e < E) {
            int d = dst[e];
            if ((unsigned)d < (unsigned)n)
                rank[e] = atomicAdd(&counts[d], 1);
        }
    } else {
        bx -= nbE;
        int colh = bx & 1;
        gemm_body<0>(X, Wsplit + (size_t)colh * WIMG, H, n, bx >> 1, colh,
                     threadIdx.x);
    }
}

// ---------------------------------------------------------------------------
// 3-pass exclusive prefix sum over counts[n] -> row_start[n]
// ---------------------------------------------------------------------------
__global__ __launch_bounds__(SCANB)
void k_scan1(const int* __restrict__ counts, int* __restrict__ row_start,
             int* __restrict__ partials, int n) {
    __shared__ int s[SCANB];
    int gid = blockIdx.x * SCANB + threadIdx.x;
    int v = (gid < n) ? counts[gid] : 0;
    s[threadIdx.x] = v;
    __syncthreads();
    for (int off = 1; off < SCANB; off <<= 1) {
        int t = (threadIdx.x >= off) ? s[threadIdx.x - off] : 0;
        __syncthreads();
        s[threadIdx.x] += t;
        __syncthreads();
    }
    if (gid < n) row_start[gid] = s[threadIdx.x] - v;
    if (threadIdx.x == SCANB - 1) partials[blockIdx.x] = s[SCANB - 1];
}

__global__ __launch_bounds__(64)
void k_scan2(int* __restrict__ partials, int nb) {     // nb <= 64
    __shared__ int s[64];
    int v = (threadIdx.x < nb) ? partials[threadIdx.x] : 0;
    s[threadIdx.x] = v;
    __syncthreads();
    for (int off = 1; off < 64; off <<= 1) {
        int t = (threadIdx.x >= off) ? s[threadIdx.x - off] : 0;
        __syncthreads();
        s[threadIdx.x] += t;
        __syncthreads();
    }
    if (threadIdx.x < nb) partials[threadIdx.x] = s[threadIdx.x] - v;
}

__global__ __launch_bounds__(SCANB)
void k_scan3(int* __restrict__ row_start, const int* __restrict__ partials, int n) {
    int gid = blockIdx.x * SCANB + threadIdx.x;
    if (gid < n) row_start[gid] += partials[blockIdx.x];
}

// atomic-free fill: edges[row_start[dst] + rank[e]] = {src, raw ew}
__global__ void k_fill(const int* __restrict__ src, const int* __restrict__ dst,
                       const float* __restrict__ ew, const int* __restrict__ row_start,
                       const int* __restrict__ rank, int2* __restrict__ edges,
                       int E, int n) {
    int e = blockIdx.x * blockDim.x + threadIdx.x;
    if (e >= E) return;
    int s = src[e], d = dst[e];
    if ((unsigned)s >= (unsigned)n || (unsigned)d >= (unsigned)n) return;
    edges[row_start[d] + rank[e]] = make_int2(s, __float_as_int(ew[e]));
}

// per-node: deg = 1 + sum(raw ew over bucket); dinv = rsqrt(deg)
__global__ void k_deg(const int* __restrict__ row_start, const int* __restrict__ counts,
                      const int2* __restrict__ edges, float* __restrict__ dinv, int n) {
    int i = blockIdx.x * blockDim.x + threadIdx.x;
    if (i >= n) return;
    int j = row_start[i], end = j + counts[i];
    float sum = 1.0f;
    for (; j < end; ++j) sum += __int_as_float(edges[j].y);
    dinv[i] = rsqrtf(sum);
}

// ---------------------------------------------------------------------------
// CSR aggregate over bf16 h:
//   out[i] = (relu?)( h[i]*di^2 + bias + di * sum_j w'_j * h[s_j] )
// FIXUP=1: w' = raw_ew * dinv[src], written back (edge owned by one node).
// 32 lanes per node (4 ch = 8 B bf16 per lane per row).
// ---------------------------------------------------------------------------
template<int RELU_OUT, int FIXUP>
__global__ __launch_bounds__(TPB)
void k_aggregate(const unsigned short* __restrict__ h, const int* __restrict__ row_start,
                 const int* __restrict__ counts, int2* __restrict__ edges,
                 const float* __restrict__ dinv, const float* __restrict__ bias,
                 float* __restrict__ out, int n) {
    int t = blockIdx.x * blockDim.x + threadIdx.x;
    int node = t >> 5;
    if (node >= n) return;
    int tx = t & 31;

    const ushort4* h4 = (const ushort4*)h;   // 32 ushort4 per row
    float di = dinv[node];
    float4 b  = ((const float4*)bias)[tx];
    float4 hv = bf4_to_f4(h4[(size_t)node * CH4 + tx]);
    float4 acc = make_float4(0.f, 0.f, 0.f, 0.f);

    int j   = row_start[node];
    int end = j + counts[node];

    for (; j + 8 <= end; j += 8) {
        int2 e[8];
        #pragma unroll
        for (int i = 0; i < 8; ++i) e[i] = edges[j + i];
        ushort4 g[8];
        #pragma unroll
        for (int i = 0; i < 8; ++i) g[i] = h4[(size_t)e[i].x * CH4 + tx];
        float w[8];
        #pragma unroll
        for (int i = 0; i < 8; ++i) {
            w[i] = __int_as_float(e[i].y);
            if (FIXUP) w[i] *= dinv[e[i].x];
        }
        if (FIXUP && tx == 0) {
            #pragma unroll
            for (int i = 0; i < 8; ++i) edges[j + i].y = __float_as_int(w[i]);
        }
        #pragma unroll
        for (int i = 0; i < 8; ++i) {
            float4 gf = bf4_to_f4(g[i]);
            acc.x += gf.x * w[i]; acc.y += gf.y * w[i];
            acc.z += gf.z * w[i]; acc.w += gf.w * w[i];
        }
    }
    if (j + 4 <= end) {
        int2 e[4];
        #pragma unroll
        for (int i = 0; i < 4; ++i) e[i] = edges[j + i];
        ushort4 g[4];
        #pragma unroll
        for (int i = 0; i < 4; ++i) g[i] = h4[(size_t)e[i].x * CH4 + tx];
        float w[4];
        #pragma unroll
        for (int i = 0; i < 4; ++i) {
            w[i] = __int_as_float(e[i].y);
            if (FIXUP) w[i] *= dinv[e[i].x];
        }
        if (FIXUP && tx == 0) {
            #pragma unroll
            for (int i = 0; i < 4; ++i) edges[j + i].y = __float_as_int(w[i]);
        }
        #pragma unroll
        for (int i = 0; i < 4; ++i) {
            float4 gf = bf4_to_f4(g[i]);
            acc.x += gf.x * w[i]; acc.y += gf.y * w[i];
            acc.z += gf.z * w[i]; acc.w += gf.w * w[i];
        }
        j += 4;
    }
    for (; j < end; ++j) {
        int2 e0 = edges[j];
        float w0 = __int_as_float(e0.y);
        if (FIXUP) w0 *= dinv[e0.x];
        if (FIXUP && tx == 0) edges[j].y = __float_as_int(w0);
        float4 gf = bf4_to_f4(h4[(size_t)e0.x * CH4 + tx]);
        acc.x += gf.x * w0; acc.y += gf.y * w0;
        acc.z += gf.z * w0; acc.w += gf.w * w0;
    }

    float sc = di * di;
    float4 o = make_float4(hv.x * sc + b.x + di * acc.x,
                           hv.y * sc + b.y + di * acc.y,
                           hv.z * sc + b.z + di * acc.z,
                           hv.w * sc + b.w + di * acc.w);
    if (RELU_OUT) {
        o.x = fmaxf(o.x, 0.f); o.y = fmaxf(o.y, 0.f);
        o.z = fmaxf(o.z, 0.f); o.w = fmaxf(o.w, 0.f);
    }
    ((float4*)out)[(size_t)node * CH4 + tx] = o;
}

// ---------------------------------------------------------------------------
extern "C" void kernel_launch(void* const* d_in, const int* in_sizes, int n_in,
                              void* d_out, int out_size, void* d_ws, size_t ws_size,
                              hipStream_t stream) {
    const float* x  = (const float*)d_in[0];   // [N,128]
    const int*   ei = (const int*)d_in[1];     // [2,E]
    const float* ew = (const float*)d_in[2];   // [E]
    const float* W1 = (const float*)d_in[3];
    const float* b1 = (const float*)d_in[4];
    const float* W2 = (const float*)d_in[5];
    const float* b2 = (const float*)d_in[6];
    float* out = (float*)d_out;                // [N,128]

    const int N = in_sizes[0] / CH;
    const int E = in_sizes[2];
    const int* src = ei;
    const int* dst = ei + E;

    // workspace layout (16B-aligned)
    size_t Np = ((size_t)N + 255) & ~(size_t)255;
    float* ws        = (float*)d_ws;
    float* dinv      = ws;                              // N floats
    unsigned short* h = (unsigned short*)(dinv + Np);   // N*CH bf16
    int*   counts    = (int*)(h + (size_t)N * CH);      // N ints
    int*   row_start = counts + Np;                     // N ints
    int*   rank      = row_start + Np;                  // E ints
    int*   partials  = rank + (((size_t)E + 63) & ~(size_t)63); // 64 ints
    int2*  edges     = (int2*)(partials + 64);          // E int2
    short* Wsplit    = (short*)(edges + E);             // 4*WIMG shorts (128 KB)

    const int nbN    = (N + TPB - 1) / TPB;
    const int nbE    = (E + TPB - 1) / TPB;
    const int nbAgg  = (int)(((size_t)N * 32 + TPB - 1) / TPB);
    const int nbScan = (N + SCANB - 1) / SCANB;
    const int nbGemm2 = 2 * ((N + 63) / 64);
    const int nbPrep  = (2 * CH * CH + TPB - 1) / TPB;

    // ---- prep ----
    hipMemsetAsync(counts, 0, (size_t)N * sizeof(int), stream);
    k_prep     <<<nbPrep, TPB, 0, stream>>>(W1, W2, Wsplit);

    // ---- fused: edge rank pass | gemm1 ----
    k_gemm_rank<<<nbE + nbGemm2, TPB, 0, stream>>>(x, Wsplit, h, N, dst,
                                                   counts, rank, E, nbE);
    // ---- CSR finalize ----
    k_scan1    <<<nbScan, SCANB, 0, stream>>>(counts, row_start, partials, N);
    k_scan2    <<<1, 64, 0, stream>>>(partials, nbScan);
    k_scan3    <<<nbScan, SCANB, 0, stream>>>(row_start, partials, N);
    k_fill     <<<nbE, TPB, 0, stream>>>(src, dst, ew, row_start, rank, edges, E, N);
    k_deg      <<<nbN, TPB, 0, stream>>>(row_start, counts, edges, dinv, N);

    // ---- layer 1 aggregate (computes+stores w' = ew*dinv[src]) ----
    k_aggregate<0,1><<<nbAgg, TPB, 0, stream>>>(h, row_start, counts, edges,
                                                dinv, b1, out, N);
    // ---- layer 2 ----
    k_gemm<1>       <<<nbGemm2, TPB, 0, stream>>>(out, Wsplit + 2 * WIMG, h, N);
    k_aggregate<1,0><<<nbAgg, TPB, 0, stream>>>(h, row_start, counts, edges,
                                                dinv, b2, out, N);
}

// Round 9
// 224.443 us; speedup vs baseline: 10.1659x; 1.0276x over previous
//
#include <hip/hip_runtime.h>
#include <math.h>

// GCN 2-layer forward on MI355X — round 9:
//  * rank atomic pass: 4-way replicated counters (contention /4)
//  * layer-1 output stored bf16 (+ReLU fused) -> gemm2 A is exact bf16,
//    dropping one Markidis term (2 MFMAs instead of 3)
//  * scan2 fused into scan3 (one fewer launch)
#define CH   128
#define CH4  32
#define TPB  256
#define SCANB 1024
#define WIMG 16384       // shorts per (layer,colh) fragment image (32 KB)
#define NREP 4

typedef __attribute__((ext_vector_type(8))) short short8;   // 8 bf16 (4 VGPRs)
typedef __attribute__((ext_vector_type(4))) float floatx4;  // MFMA acc

// round-to-nearest-even fp32 -> bf16 (bit pattern)
static __device__ __forceinline__ unsigned short f2bf(float f) {
    unsigned u = __float_as_uint(f);
    return (unsigned short)((u + 0x7fffu + ((u >> 16) & 1u)) >> 16);
}
static __device__ __forceinline__ float bf2f(unsigned short s) {
    return __uint_as_float(((unsigned)s) << 16);
}
static __device__ __forceinline__ float4 bf4_to_f4(ushort4 u) {
    return make_float4(bf2f(u.x), bf2f(u.y), bf2f(u.z), bf2f(u.w));
}

// ---------------------------------------------------------------------------
// k_prep: split W1,W2 into bf16 hi/lo B-fragment images (32 KB per colh).
// ---------------------------------------------------------------------------
__global__ void k_prep(const float* __restrict__ W1, const float* __restrict__ W2,
                       short* __restrict__ Wsplit) {
    int i = blockIdx.x * blockDim.x + threadIdx.x;   // over 2*128*128
    if (i >= 2 * CH * CH) return;
    int layer = i >> 14;
    int idx   = i & 16383;
    int k = idx >> 7, c = idx & 127;
    float w = (layer ? W2 : W1)[k * CH + c];
    unsigned short hi = f2bf(w);
    unsigned short lo = f2bf(w - bf2f(hi));
    int colh = c >> 6, nn = c & 63;
    int kt = k >> 5, q = (k & 31) >> 3, j = k & 7;
    int ns = nn >> 4, ln = q * 16 + (nn & 15);
    size_t base = (size_t)(layer * 2 + colh) * WIMG;
    size_t off  = ((size_t)(kt * 4 + ns) * 64 + ln) * 8 + j;
    Wsplit[base + off]        = (short)hi;
    Wsplit[base + 8192 + off] = (short)lo;
}

// ---------------------------------------------------------------------------
// shared W-staging: contiguous 32 KB copy of the pre-split fragment image
// ---------------------------------------------------------------------------
#define STAGE_W(sW, Wfrag, tid)                                    \
    {                                                              \
        const float4* gsrc = (const float4*)(Wfrag);               \
        float4* ldst = (float4*)(sW);                              \
        _Pragma("unroll")                                          \
        for (int i = 0; i < 8; ++i)                                \
            ldst[i * TPB + (tid)] = gsrc[i * TPB + (tid)];         \
    }

// ---------------------------------------------------------------------------
// fp32-input MFMA GEMM body (3-term Markidis split), bf16 output.
// Frag layouts (m89/m91/m120-verified):
//   A: m=lane&15, k=(lane>>4)*8+j ; B mirrored ; D: col=lane&15, row=(lane>>4)*4+reg
// ---------------------------------------------------------------------------
static __device__ __forceinline__ void gemm_body_f32(
        const float* __restrict__ X, const short* __restrict__ Wfrag,
        unsigned short* __restrict__ H, int n, int tile, int colh, int tid) {
    __shared__ __align__(16) short sW[2][4][4][64][8];   // 32 KB
    STAGE_W(sW, Wfrag, tid);
    __syncthreads();

    const int lane = tid & 63;
    const int wv   = tid >> 6;
    const int q    = lane >> 4;
    const int m    = lane & 15;
    const int row0 = tile * 64 + wv * 16;
    if (row0 >= n) return;

    int rrow = row0 + m;
    if (rrow > n - 1) rrow = n - 1;

    const float4* xr = (const float4*)(X + (size_t)rrow * CH);
    float4 xa[4][2];
    #pragma unroll
    for (int kt = 0; kt < 4; ++kt) {
        xa[kt][0] = xr[kt * 8 + q * 2 + 0];
        xa[kt][1] = xr[kt * 8 + q * 2 + 1];
    }

    floatx4 acc[4];
    #pragma unroll
    for (int ns = 0; ns < 4; ++ns) acc[ns] = (floatx4){0.f, 0.f, 0.f, 0.f};

    #pragma unroll
    for (int kt = 0; kt < 4; ++kt) {
        float xf[8] = { xa[kt][0].x, xa[kt][0].y, xa[kt][0].z, xa[kt][0].w,
                        xa[kt][1].x, xa[kt][1].y, xa[kt][1].z, xa[kt][1].w };
        short8 ah, al;
        #pragma unroll
        for (int j = 0; j < 8; ++j) {
            float v = xf[j];
            unsigned short h = f2bf(v);
            ah[j] = (short)h;
            al[j] = (short)f2bf(v - bf2f(h));
        }
        #pragma unroll
        for (int ns = 0; ns < 4; ++ns) {
            short8 bh = *(const short8*)&sW[0][kt][ns][lane][0];
            short8 bl = *(const short8*)&sW[1][kt][ns][lane][0];
            acc[ns] = __builtin_amdgcn_mfma_f32_16x16x32_bf16(ah, bh, acc[ns], 0, 0, 0);
            acc[ns] = __builtin_amdgcn_mfma_f32_16x16x32_bf16(al, bh, acc[ns], 0, 0, 0);
            acc[ns] = __builtin_amdgcn_mfma_f32_16x16x32_bf16(ah, bl, acc[ns], 0, 0, 0);
        }
    }

    #pragma unroll
    for (int ns = 0; ns < 4; ++ns) {
        #pragma unroll
        for (int reg = 0; reg < 4; ++reg) {
            int r = row0 + q * 4 + reg;
            if (r < n)
                H[(size_t)r * CH + colh * 64 + ns * 16 + m] = f2bf(acc[ns][reg]);
        }
    }
}

// bf16-input variant: A is exact bf16 -> no low term, 2 MFMAs per fragment.
static __device__ __forceinline__ void gemm_body_bf(
        const unsigned short* __restrict__ X, const short* __restrict__ Wfrag,
        unsigned short* __restrict__ H, int n, int tile, int colh, int tid) {
    __shared__ __align__(16) short sW[2][4][4][64][8];   // 32 KB
    STAGE_W(sW, Wfrag, tid);
    __syncthreads();

    const int lane = tid & 63;
    const int wv   = tid >> 6;
    const int q    = lane >> 4;
    const int m    = lane & 15;
    const int row0 = tile * 64 + wv * 16;
    if (row0 >= n) return;

    int rrow = row0 + m;
    if (rrow > n - 1) rrow = n - 1;

    const ushort4* xr = (const ushort4*)(X + (size_t)rrow * CH);
    short8 a[4];
    #pragma unroll
    for (int kt = 0; kt < 4; ++kt) {
        ushort4 u0 = xr[kt * 8 + q * 2 + 0];
        ushort4 u1 = xr[kt * 8 + q * 2 + 1];
        a[kt][0] = (short)u0.x; a[kt][1] = (short)u0.y;
        a[kt][2] = (short)u0.z; a[kt][3] = (short)u0.w;
        a[kt][4] = (short)u1.x; a[kt][5] = (short)u1.y;
        a[kt][6] = (short)u1.z; a[kt][7] = (short)u1.w;
    }

    floatx4 acc[4];
    #pragma unroll
    for (int ns = 0; ns < 4; ++ns) acc[ns] = (floatx4){0.f, 0.f, 0.f, 0.f};

    #pragma unroll
    for (int kt = 0; kt < 4; ++kt) {
        #pragma unroll
        for (int ns = 0; ns < 4; ++ns) {
            short8 bh = *(const short8*)&sW[0][kt][ns][lane][0];
            short8 bl = *(const short8*)&sW[1][kt][ns][lane][0];
            acc[ns] = __builtin_amdgcn_mfma_f32_16x16x32_bf16(a[kt], bh, acc[ns], 0, 0, 0);
            acc[ns] = __builtin_amdgcn_mfma_f32_16x16x32_bf16(a[kt], bl, acc[ns], 0, 0, 0);
        }
    }

    #pragma unroll
    for (int ns = 0; ns < 4; ++ns) {
        #pragma unroll
        for (int reg = 0; reg < 4; ++reg) {
            int r = row0 + q * 4 + reg;
            if (r < n)
                H[(size_t)r * CH + colh * 64 + ns * 16 + m] = f2bf(acc[ns][reg]);
        }
    }
}

// fused: blocks [0, nbE) do the replicated rank atomic (long pole, first);
// blocks [nbE, nbE+ngemm2) do gemm1 (fp32 x).
__global__ __launch_bounds__(TPB, 4)
void k_gemm_rank(const float* __restrict__ X, const short* __restrict__ Wsplit,
                 unsigned short* __restrict__ H, int n,
                 const int* __restrict__ dst, int* __restrict__ counts_rep,
                 int* __restrict__ rank, int E, int nbE, int Np) {
    int bx = blockIdx.x;
    if (bx < nbE) {
        int e = bx * TPB + threadIdx.x;
        if (e < E) {
            int d = dst[e];
            if ((unsigned)d < (unsigned)n) {
                int rep = e & (NREP - 1);
                rank[e] = atomicAdd(&counts_rep[rep * Np + d], 1);
            }
        }
    } else {
        bx -= nbE;
        int colh = bx & 1;
        gemm_body_f32(X, Wsplit + (size_t)colh * WIMG, H, n, bx >> 1, colh,
                      threadIdx.x);
    }
}

__global__ __launch_bounds__(TPB, 4)
void k_gemm_bf(const unsigned short* __restrict__ X, const short* __restrict__ Wsplit,
               unsigned short* __restrict__ H, int n) {
    int colh = (int)blockIdx.x & 1;
    gemm_body_bf(X, Wsplit + (size_t)colh * WIMG, H, n,
                 (int)blockIdx.x >> 1, colh, threadIdx.x);
}

// ---------------------------------------------------------------------------
// scan pass 1: sum the NREP replica counts, block-exclusive-scan the totals,
// emit per-node replica offsets + total counts.
// ---------------------------------------------------------------------------
__global__ __launch_bounds__(SCANB)
void k_scan1(const int* __restrict__ counts_rep, int Np,
             int* __restrict__ counts_tot, int4* __restrict__ repoff,
             int* __restrict__ row_start, int* __restrict__ partials, int n) {
    __shared__ int s[SCANB];
    int gid = blockIdx.x * SCANB + threadIdx.x;
    int c0 = 0, c1 = 0, c2 = 0, c3 = 0;
    if (gid < n) {
        c0 = counts_rep[gid];
        c1 = counts_rep[Np + gid];
        c2 = counts_rep[2 * Np + gid];
        c3 = counts_rep[3 * Np + gid];
    }
    int v = c0 + c1 + c2 + c3;
    s[threadIdx.x] = v;
    __syncthreads();
    for (int off = 1; off < SCANB; off <<= 1) {
        int t = (threadIdx.x >= off) ? s[threadIdx.x - off] : 0;
        __syncthreads();
        s[threadIdx.x] += t;
        __syncthreads();
    }
    if (gid < n) {
        row_start[gid]  = s[threadIdx.x] - v;
        counts_tot[gid] = v;
        repoff[gid]     = make_int4(0, c0, c0 + c1, c0 + c1 + c2);
    }
    if (threadIdx.x == SCANB - 1) partials[blockIdx.x] = s[SCANB - 1];
}

// scan3 with fused scan2: base = sum of partials before this block (nb <= 64)
__global__ __launch_bounds__(SCANB)
void k_scan3(int* __restrict__ row_start, const int* __restrict__ partials, int n) {
    __shared__ int sbase;
    if (threadIdx.x < 64) {
        int v = (threadIdx.x < blockIdx.x) ? partials[threadIdx.x] : 0;
        #pragma unroll
        for (int off = 32; off; off >>= 1) v += __shfl_down(v, off, 64);
        if (threadIdx.x == 0) sbase = v;
    }
    __syncthreads();
    int gid = blockIdx.x * SCANB + threadIdx.x;
    if (gid < n) row_start[gid] += sbase;
}

// atomic-free fill: edges[row_start[d] + repoff[rep][d] + rank[e]] = {src, ew}
__global__ void k_fill(const int* __restrict__ src, const int* __restrict__ dst,
                       const float* __restrict__ ew, const int* __restrict__ row_start,
                       const int4* __restrict__ repoff, const int* __restrict__ rank,
                       int2* __restrict__ edges, int E, int n) {
    int e = blockIdx.x * blockDim.x + threadIdx.x;
    if (e >= E) return;
    int s = src[e], d = dst[e];
    if ((unsigned)s >= (unsigned)n || (unsigned)d >= (unsigned)n) return;
    int rep = e & (NREP - 1);
    int4 ro = repoff[d];
    int roa[4] = {ro.x, ro.y, ro.z, ro.w};
    edges[row_start[d] + roa[rep] + rank[e]] = make_int2(s, __float_as_int(ew[e]));
}

// per-node: deg = 1 + sum(raw ew over bucket); dinv = rsqrt(deg)
__global__ void k_deg(const int* __restrict__ row_start, const int* __restrict__ counts,
                      const int2* __restrict__ edges, float* __restrict__ dinv, int n) {
    int i = blockIdx.x * blockDim.x + threadIdx.x;
    if (i >= n) return;
    int j = row_start[i], end = j + counts[i];
    float sum = 1.0f;
    for (; j < end; ++j) sum += __int_as_float(edges[j].y);
    dinv[i] = rsqrtf(sum);
}

// ---------------------------------------------------------------------------
// CSR aggregate over bf16 h:
//   out[i] = (relu?)( h[i]*di^2 + bias + di * sum_j w'_j * h[s_j] )
// FIXUP=1: w' = raw_ew * dinv[src], written back. OUT_BF16: store bf16.
// ---------------------------------------------------------------------------
template<int RELU_OUT, int FIXUP, int OUT_BF16>
__global__ __launch_bounds__(TPB)
void k_aggregate(const unsigned short* __restrict__ h, const int* __restrict__ row_start,
                 const int* __restrict__ counts, int2* __restrict__ edges,
                 const float* __restrict__ dinv, const float* __restrict__ bias,
                 void* __restrict__ out, int n) {
    int t = blockIdx.x * blockDim.x + threadIdx.x;
    int node = t >> 5;
    if (node >= n) return;
    int tx = t & 31;

    const ushort4* h4 = (const ushort4*)h;
    float di = dinv[node];
    float4 b  = ((const float4*)bias)[tx];
    float4 hv = bf4_to_f4(h4[(size_t)node * CH4 + tx]);
    float4 acc = make_float4(0.f, 0.f, 0.f, 0.f);

    int j   = row_start[node];
    int end = j + counts[node];

    for (; j + 8 <= end; j += 8) {
        int2 e[8];
        #pragma unroll
        for (int i = 0; i < 8; ++i) e[i] = edges[j + i];
        ushort4 g[8];
        #pragma unroll
        for (int i = 0; i < 8; ++i) g[i] = h4[(size_t)e[i].x * CH4 + tx];
        float w[8];
        #pragma unroll
        for (int i = 0; i < 8; ++i) {
            w[i] = __int_as_float(e[i].y);
            if (FIXUP) w[i] *= dinv[e[i].x];
        }
        if (FIXUP && tx == 0) {
            #pragma unroll
            for (int i = 0; i < 8; ++i) edges[j + i].y = __float_as_int(w[i]);
        }
        #pragma unroll
        for (int i = 0; i < 8; ++i) {
            float4 gf = bf4_to_f4(g[i]);
            acc.x += gf.x * w[i]; acc.y += gf.y * w[i];
            acc.z += gf.z * w[i]; acc.w += gf.w * w[i];
        }
    }
    if (j + 4 <= end) {
        int2 e[4];
        #pragma unroll
        for (int i = 0; i < 4; ++i) e[i] = edges[j + i];
        ushort4 g[4];
        #pragma unroll
        for (int i = 0; i < 4; ++i) g[i] = h4[(size_t)e[i].x * CH4 + tx];
        float w[4];
        #pragma unroll
        for (int i = 0; i < 4; ++i) {
            w[i] = __int_as_float(e[i].y);
            if (FIXUP) w[i] *= dinv[e[i].x];
        }
        if (FIXUP && tx == 0) {
            #pragma unroll
            for (int i = 0; i < 4; ++i) edges[j + i].y = __float_as_int(w[i]);
        }
        #pragma unroll
        for (int i = 0; i < 4; ++i) {
            float4 gf = bf4_to_f4(g[i]);
            acc.x += gf.x * w[i]; acc.y += gf.y * w[i];
            acc.z += gf.z * w[i]; acc.w += gf.w * w[i];
        }
        j += 4;
    }
    for (; j < end; ++j) {
        int2 e0 = edges[j];
        float w0 = __int_as_float(e0.y);
        if (FIXUP) w0 *= dinv[e0.x];
        if (FIXUP && tx == 0) edges[j].y = __float_as_int(w0);
        float4 gf = bf4_to_f4(h4[(size_t)e0.x * CH4 + tx]);
        acc.x += gf.x * w0; acc.y += gf.y * w0;
        acc.z += gf.z * w0; acc.w += gf.w * w0;
    }

    float sc = di * di;
    float4 o = make_float4(hv.x * sc + b.x + di * acc.x,
                           hv.y * sc + b.y + di * acc.y,
                           hv.z * sc + b.z + di * acc.z,
                           hv.w * sc + b.w + di * acc.w);
    if (RELU_OUT) {
        o.x = fmaxf(o.x, 0.f); o.y = fmaxf(o.y, 0.f);
        o.z = fmaxf(o.z, 0.f); o.w = fmaxf(o.w, 0.f);
    }
    if (OUT_BF16) {
        ushort4 u = make_ushort4(f2bf(o.x), f2bf(o.y), f2bf(o.z), f2bf(o.w));
        ((ushort4*)out)[(size_t)node * CH4 + tx] = u;
    } else {
        ((float4*)out)[(size_t)node * CH4 + tx] = o;
    }
}

// ---------------------------------------------------------------------------
extern "C" void kernel_launch(void* const* d_in, const int* in_sizes, int n_in,
                              void* d_out, int out_size, void* d_ws, size_t ws_size,
                              hipStream_t stream) {
    const float* x  = (const float*)d_in[0];   // [N,128]
    const int*   ei = (const int*)d_in[1];     // [2,E]
    const float* ew = (const float*)d_in[2];   // [E]
    const float* W1 = (const float*)d_in[3];
    const float* b1 = (const float*)d_in[4];
    const float* W2 = (const float*)d_in[5];
    const float* b2 = (const float*)d_in[6];
    float* out = (float*)d_out;                // [N,128]

    const int N = in_sizes[0] / CH;
    const int E = in_sizes[2];
    const int* src = ei;
    const int* dst = ei + E;

    // workspace layout (16B-aligned)
    size_t Np = ((size_t)N + 255) & ~(size_t)255;
    size_t Ep = ((size_t)E + 63) & ~(size_t)63;
    float* ws          = (float*)d_ws;
    float* dinv        = ws;                                // Np floats
    unsigned short* h  = (unsigned short*)(dinv + Np);      // N*CH bf16
    unsigned short* o1 = h + (size_t)N * CH;                // N*CH bf16
    int*  counts_rep   = (int*)(o1 + (size_t)N * CH);       // NREP*Np ints
    int*  counts_tot   = counts_rep + NREP * Np;            // Np ints
    int*  row_start    = counts_tot + Np;                   // Np ints
    int4* repoff       = (int4*)(row_start + Np);           // Np int4
    int*  rank         = (int*)(repoff + Np);               // Ep ints
    int*  partials     = rank + Ep;                         // 64 ints
    int2* edges        = (int2*)(partials + 64);            // E int2
    short* Wsplit      = (short*)(edges + E);               // 4*WIMG shorts

    const int nbN    = (N + TPB - 1) / TPB;
    const int nbE    = (E + TPB - 1) / TPB;
    const int nbAgg  = (int)(((size_t)N * 32 + TPB - 1) / TPB);
    const int nbScan = (N + SCANB - 1) / SCANB;     // 49 <= 64
    const int nbGemm2 = 2 * ((N + 63) / 64);
    const int nbPrep  = (2 * CH * CH + TPB - 1) / TPB;

    // ---- prep ----
    hipMemsetAsync(counts_rep, 0, (size_t)NREP * Np * sizeof(int), stream);
    k_prep     <<<nbPrep, TPB, 0, stream>>>(W1, W2, Wsplit);

    // ---- fused: replicated rank pass | gemm1 (h = x@W1, bf16) ----
    k_gemm_rank<<<nbE + nbGemm2, TPB, 0, stream>>>(x, Wsplit, h, N, dst,
                                                   counts_rep, rank, E, nbE, (int)Np);
    // ---- CSR finalize ----
    k_scan1    <<<nbScan, SCANB, 0, stream>>>(counts_rep, (int)Np, counts_tot,
                                              repoff, row_start, partials, N);
    k_scan3    <<<nbScan, SCANB, 0, stream>>>(row_start, partials, N);
    k_fill     <<<nbE, TPB, 0, stream>>>(src, dst, ew, row_start, repoff, rank,
                                         edges, E, N);
    k_deg      <<<nbN, TPB, 0, stream>>>(row_start, counts_tot, edges, dinv, N);

    // ---- layer 1 aggregate: o1 = relu(agg(h)) in bf16; stores w' ----
    k_aggregate<1,1,1><<<nbAgg, TPB, 0, stream>>>(h, row_start, counts_tot, edges,
                                                  dinv, b1, o1, N);
    // ---- layer 2 ----
    k_gemm_bf         <<<nbGemm2, TPB, 0, stream>>>(o1, Wsplit + 2 * WIMG, h, N);
    k_aggregate<1,0,0><<<nbAgg, TPB, 0, stream>>>(h, row_start, counts_tot, edges,
                                                  dinv, b2, out, N);
}